// Round 1
// baseline (14067.336 us; speedup 1.0000x reference)
//
#include <hip/hip_runtime.h>
#include <math.h>

// Problem constants
#define B_   8
#define L_   1024
#define NS_  512
#define D_   512
#define NH_  8
#define HD_  64
#define DN_  256
#define E_   8
#define K_   2
#define HE_  2048
#define EPS_ 1e-5f

// ---------------------------------------------------------------------------
// Kernel 1: noise embedding + AdaLN modulation vectors + router top-2
// grid: (B), block: 256
// ---------------------------------------------------------------------------
__global__ __launch_bounds__(256) void noise_kernel(
    const float* __restrict__ t_in,
    const float* __restrict__ w1, const float* __restrict__ b1,
    const float* __restrict__ w2, const float* __restrict__ b2,
    const float* __restrict__ ncsa_w, const float* __restrict__ ncsa_b,
    const float* __restrict__ moe_w, const float* __restrict__ moe_b,
    const float* __restrict__ rw,
    float* __restrict__ ncsa_mod, float* __restrict__ moe_mod,
    float* __restrict__ tw_out, int* __restrict__ ti_out)
{
  const int b = blockIdx.x;
  const int t = threadIdx.x;
  __shared__ float temb[512];
  __shared__ float h1[256];
  __shared__ float ncs[256];
  const float tv = t_in[b];
  {
    // freqs[i] = exp(-ln(10000) * i / 255), temb = [cos(ang), sin(ang)]
    float fr = __expf(-logf(10000.0f) * (float)t / 255.0f);
    float ang = tv * fr;
    temb[t] = cosf(ang);
    temb[256 + t] = sinf(ang);
  }
  __syncthreads();
  {
    float s = b1[t];
    for (int i = 0; i < 512; ++i) s += temb[i] * w1[i * 256 + t];
    h1[t] = s / (1.0f + __expf(-s));  // silu
  }
  __syncthreads();
  {
    float s = b2[t];
    for (int i = 0; i < 256; ++i) s += h1[i] * w2[i * 256 + t];
    ncs[t] = s;
  }
  __syncthreads();
  for (int m = t; m < 1024; m += 256) {
    float s1 = ncsa_b[m], s2 = moe_b[m];
    for (int i = 0; i < 256; ++i) {
      float v = ncs[i];
      s1 += v * ncsa_w[i * 1024 + m];
      s2 += v * moe_w[i * 1024 + m];
    }
    ncsa_mod[b * 1024 + m] = s1;
    moe_mod[b * 1024 + m] = s2;
  }
  if (t == 0) {
    float lg[8];
    for (int e = 0; e < 8; ++e) {
      float s = 0.f;
      for (int i = 0; i < 256; ++i) s += ncs[i] * rw[i * 8 + e];
      lg[e] = s;
    }
    float mx = lg[0];
    for (int e = 1; e < 8; ++e) mx = fmaxf(mx, lg[e]);
    float z = 0.f, p[8];
    for (int e = 0; e < 8; ++e) { p[e] = __expf(lg[e] - mx); z += p[e]; }
    for (int e = 0; e < 8; ++e) p[e] /= z;
    int i0 = 0;
    for (int e = 1; e < 8; ++e) if (p[e] > p[i0]) i0 = e;   // ties -> lower idx, matches lax.top_k
    int i1 = (i0 == 0) ? 1 : 0;
    for (int e = 0; e < 8; ++e) if (e != i0 && p[e] > p[i1]) i1 = e;
    float s01 = fmaxf(p[i0] + p[i1], 1e-8f);
    tw_out[b * 2 + 0] = p[i0] / s01;
    tw_out[b * 2 + 1] = p[i1] / s01;
    ti_out[b * 2 + 0] = i0;
    ti_out[b * 2 + 1] = i1;
  }
}

// ---------------------------------------------------------------------------
// Kernel 2: LayerNorm + modulation.  mod==nullptr: y=ln(x)*g+b (per-feature)
//           mod!=nullptr: y=ln(x)*(1+mod[b,512+d]) + mod[b,d]   (AdaLN)
// grid: (B*L), block: 256 (2 elems/thread)
// ---------------------------------------------------------------------------
__global__ __launch_bounds__(256) void ln_mod_kernel(
    const float* __restrict__ X, const float* __restrict__ gvec,
    const float* __restrict__ bvec, const float* __restrict__ mod,
    float* __restrict__ Y)
{
  const int row = blockIdx.x;
  const int b = row >> 10;
  const int t = threadIdx.x;
  const float* xr = X + (size_t)row * 512;
  float2 v = *(const float2*)(xr + t * 2);
  float s = v.x + v.y;
  float q = v.x * v.x + v.y * v.y;
#pragma unroll
  for (int off = 32; off > 0; off >>= 1) {
    s += __shfl_down(s, off, 64);
    q += __shfl_down(q, off, 64);
  }
  __shared__ float ws_[4], wq_[4], smu[1], sinv[1];
  if ((t & 63) == 0) { ws_[t >> 6] = s; wq_[t >> 6] = q; }
  __syncthreads();
  if (t == 0) {
    float S = ws_[0] + ws_[1] + ws_[2] + ws_[3];
    float Q = wq_[0] + wq_[1] + wq_[2] + wq_[3];
    float mu = S * (1.0f / 512.0f);
    float var = Q * (1.0f / 512.0f) - mu * mu;
    smu[0] = mu;
    sinv[0] = rsqrtf(var + EPS_);
  }
  __syncthreads();
  const float mu = smu[0], inv = sinv[0];
  const int d0 = t * 2;
  float scx, scy, shx, shy;
  if (mod) {
    const float* mrow = mod + (size_t)b * 1024;
    scx = 1.0f + mrow[512 + d0]; scy = 1.0f + mrow[512 + d0 + 1];
    shx = mrow[d0];              shy = mrow[d0 + 1];
  } else {
    scx = gvec[d0]; scy = gvec[d0 + 1];
    shx = bvec[d0]; shy = bvec[d0 + 1];
  }
  float2 o;
  o.x = (v.x - mu) * inv * scx + shx;
  o.y = (v.y - mu) * inv * scy + shy;
  *(float2*)(Y + (size_t)row * 512 + d0) = o;
}

// ---------------------------------------------------------------------------
// Kernel 3: generic fp32 GEMM  C[M,N] = A[M,Kd] @ W[Kd,N] + bias (+ resid)
// 64x64 block tile, BK=16, 256 threads, 4x4 per thread.
// M,N multiples of 64; Kd multiple of 16.
// ---------------------------------------------------------------------------
__global__ __launch_bounds__(256) void gemm_bias(
    const float* __restrict__ A, const float* __restrict__ W,
    const float* __restrict__ bias, const float* __restrict__ resid,
    float* __restrict__ C, int M, int Kd, int N)
{
  __shared__ float As[16][68];  // [k][m], padded to keep float4 alignment
  __shared__ float Ws[16][64];  // [k][n]
  const int t = threadIdx.x;
  const int tx = t & 15, ty = t >> 4;
  const int bm = blockIdx.y * 64;
  const int bn = blockIdx.x * 64;
  float acc[4][4] = {{0.f}};
  for (int k0 = 0; k0 < Kd; k0 += 16) {
    {
      int r = t >> 2, c = (t & 3) * 4;
      float4 av = *(const float4*)(A + (size_t)(bm + r) * Kd + k0 + c);
      As[c + 0][r] = av.x;
      As[c + 1][r] = av.y;
      As[c + 2][r] = av.z;
      As[c + 3][r] = av.w;
    }
    {
      int kr = t >> 4, c = (t & 15) * 4;
      *(float4*)&Ws[kr][c] = *(const float4*)(W + (size_t)(k0 + kr) * N + bn + c);
    }
    __syncthreads();
#pragma unroll
    for (int kk = 0; kk < 16; ++kk) {
      float4 a4 = *(const float4*)&As[kk][ty * 4];
      float4 b4 = *(const float4*)&Ws[kk][tx * 4];
      float av[4] = {a4.x, a4.y, a4.z, a4.w};
      float bv[4] = {b4.x, b4.y, b4.z, b4.w};
#pragma unroll
      for (int i = 0; i < 4; ++i)
#pragma unroll
        for (int j = 0; j < 4; ++j) acc[i][j] = fmaf(av[i], bv[j], acc[i][j]);
    }
    __syncthreads();
  }
  float4 bb = *(const float4*)(bias + bn + tx * 4);
#pragma unroll
  for (int i = 0; i < 4; ++i) {
    size_t row = (size_t)(bm + ty * 4 + i);
    float4 o;
    o.x = acc[i][0] + bb.x;
    o.y = acc[i][1] + bb.y;
    o.z = acc[i][2] + bb.z;
    o.w = acc[i][3] + bb.w;
    if (resid) {
      float4 rv = *(const float4*)(resid + row * N + bn + tx * 4);
      o.x += rv.x; o.y += rv.y; o.z += rv.z; o.w += rv.w;
    }
    *(float4*)(C + row * N + bn + tx * 4) = o;
  }
}

// ---------------------------------------------------------------------------
// Kernel 4: attention (per query row).  Q:[B,L,512]  K,V:[B,Lk,512]
// head h = cols h*64..h*64+63, scale 1/8.  grid: (L, NH, B), block 256.
// ---------------------------------------------------------------------------
__global__ __launch_bounds__(256) void attn_kernel(
    const float* __restrict__ Q, const float* __restrict__ Kmat,
    const float* __restrict__ V, float* __restrict__ O, int Lk)
{
  const int qi = blockIdx.x, h = blockIdx.y, b = blockIdx.z;
  const int t = threadIdx.x;
  __shared__ float qv[64];
  __shared__ float sc[1024];
  __shared__ float pv[4][64];
  __shared__ float wred[4];
  __shared__ float bcast[1];
  const size_t hoff = (size_t)h * 64;
  const float* qp = Q + ((size_t)b * 1024 + qi) * 512 + hoff;
  if (t < 64) qv[t] = qp[t];
  __syncthreads();
  const float* Kb = Kmat + (size_t)b * Lk * 512 + hoff;
  for (int kk = t; kk < Lk; kk += 256) {
    const float* kr = Kb + (size_t)kk * 512;
    float s = 0.f;
#pragma unroll
    for (int d = 0; d < 64; d += 4) {
      float4 k4 = *(const float4*)(kr + d);
      s += qv[d] * k4.x + qv[d + 1] * k4.y + qv[d + 2] * k4.z + qv[d + 3] * k4.w;
    }
    sc[kk] = s * 0.125f;  // 1/sqrt(64)
  }
  __syncthreads();
  float m = -1e30f;
  for (int kk = t; kk < Lk; kk += 256) m = fmaxf(m, sc[kk]);
#pragma unroll
  for (int off = 32; off > 0; off >>= 1) m = fmaxf(m, __shfl_down(m, off, 64));
  if ((t & 63) == 0) wred[t >> 6] = m;
  __syncthreads();
  if (t == 0) bcast[0] = fmaxf(fmaxf(wred[0], wred[1]), fmaxf(wred[2], wred[3]));
  __syncthreads();
  const float mx = bcast[0];
  float ssum = 0.f;
  for (int kk = t; kk < Lk; kk += 256) {
    float e = __expf(sc[kk] - mx);
    sc[kk] = e;
    ssum += e;
  }
#pragma unroll
  for (int off = 32; off > 0; off >>= 1) ssum += __shfl_down(ssum, off, 64);
  if ((t & 63) == 0) wred[t >> 6] = ssum;
  __syncthreads();
  if (t == 0) bcast[0] = wred[0] + wred[1] + wred[2] + wred[3];
  __syncthreads();
  const float inv_total = 1.0f / bcast[0];
  const int d = t & 63, s4 = t >> 6;
  const float* Vb = V + (size_t)b * Lk * 512 + hoff + d;
  float a = 0.f;
  for (int kk = s4; kk < Lk; kk += 4) a += sc[kk] * Vb[(size_t)kk * 512];
  pv[s4][d] = a;
  __syncthreads();
  if (t < 64) {
    float o = (pv[0][t] + pv[1][t] + pv[2][t] + pv[3][t]) * inv_total;
    O[((size_t)b * 1024 + qi) * 512 + hoff + t] = o;
  }
}

// ---------------------------------------------------------------------------
// Kernel 5: fused MoE.  Per block: 16 rows of one batch sample.
//  - AdaLN-LN of x2 in LDS
//  - for k in 0..1: expert e=ti[b,k]:  h = xs@Wi+bi, hid = val*silu(gate)*w
//    (chunked over HE in 256-col chunks, staged in LDS), eo += hid@Wo
//  - out = x2 + eo + sum_k w*bo[e]
// grid: (L/16, B), block 256.  Thread layout:
//   fc_in phase : thread t owns hid column t of the chunk (16 rows)
//   fc_out phase: thread t owns output cols {2t, 2t+1} (16 rows)
// ---------------------------------------------------------------------------
__global__ __launch_bounds__(256, 2) void moe_kernel(
    const float* __restrict__ X2, const float* __restrict__ mod,
    const float* __restrict__ tw, const int* __restrict__ ti,
    const float* __restrict__ Wi, const float* __restrict__ Bi,
    const float* __restrict__ Wo, const float* __restrict__ Bo,
    float* __restrict__ Out)
{
  const int b = blockIdx.y;
  const int r0 = blockIdx.x * 16;
  const int t = threadIdx.x;
  __shared__ float xs[16][516];   // 512 + pad (keeps rows 16B-aligned)
  __shared__ float hid[16][256];
  __shared__ float redS[16][16];
  __shared__ float redQ[16][16];
  __shared__ float rmu[16], rinv[16];

  // --- load x2 tile (coalesced) ---
  for (int idx = t; idx < 16 * 512; idx += 256) {
    int r = idx >> 9, d = idx & 511;
    xs[r][d] = X2[(((size_t)b * 1024) + r0 + r) * 512 + d];
  }
  __syncthreads();
  const int rr = t >> 4, li = t & 15;
  {
    float s = 0.f, q = 0.f;
    for (int j = 0; j < 32; ++j) {
      float v = xs[rr][li * 32 + j];
      s += v; q += v * v;
    }
    redS[rr][li] = s; redQ[rr][li] = q;
  }
  __syncthreads();
  if (t < 16) {
    float s = 0.f, q = 0.f;
    for (int i = 0; i < 16; ++i) { s += redS[t][i]; q += redQ[t][i]; }
    float mu = s * (1.0f / 512.0f);
    float var = q * (1.0f / 512.0f) - mu * mu;
    rmu[t] = mu;
    rinv[t] = rsqrtf(var + EPS_);
  }
  __syncthreads();
  {
    float mu = rmu[rr], inv = rinv[rr];
    const float* mrow = mod + (size_t)b * 1024;
    for (int j = 0; j < 32; ++j) {
      int d = li * 32 + j;
      float v = (xs[rr][d] - mu) * inv;
      xs[rr][d] = v * (1.0f + mrow[512 + d]) + mrow[d];
    }
  }
  __syncthreads();

  float eo0[16], eo1[16];
#pragma unroll
  for (int r = 0; r < 16; ++r) { eo0[r] = 0.f; eo1[r] = 0.f; }

  for (int k = 0; k < 2; ++k) {
    const int e = ti[b * 2 + k];
    const float w = tw[b * 2 + k];
    const float* wi = Wi + (size_t)e * 512 * 4096;
    const float* wo = Wo + (size_t)e * 2048 * 512;
    const float* bi = Bi + (size_t)e * 4096;
#pragma unroll 1
    for (int c = 0; c < 2048; c += 256) {
      float vacc[16], gacc[16];
      const float bv = bi[c + t], bg = bi[2048 + c + t];
#pragma unroll
      for (int r = 0; r < 16; ++r) { vacc[r] = bv; gacc[r] = bg; }
#pragma unroll 1
      for (int d = 0; d < 512; d += 4) {
        float4 xv[16];
#pragma unroll
        for (int r = 0; r < 16; ++r) xv[r] = *(const float4*)&xs[r][d];
#pragma unroll
        for (int dd = 0; dd < 4; ++dd) {
          float wv = wi[(size_t)(d + dd) * 4096 + c + t];
          float wg = wi[(size_t)(d + dd) * 4096 + 2048 + c + t];
#pragma unroll
          for (int r = 0; r < 16; ++r) {
            float xc = (&xv[r].x)[dd];
            vacc[r] = fmaf(xc, wv, vacc[r]);
            gacc[r] = fmaf(xc, wg, gacc[r]);
          }
        }
      }
      __syncthreads();  // previous chunk's fc_out readers of hid are done
#pragma unroll
      for (int r = 0; r < 16; ++r) {
        float g = gacc[r];
        float hv = vacc[r] * (g / (1.0f + __expf(-g)));  // val * silu(gate)
        hid[r][t] = w * hv;                               // fold router weight in
      }
      __syncthreads();
#pragma unroll 1
      for (int j = 0; j < 256; j += 4) {
        float4 hv[16];
#pragma unroll
        for (int r = 0; r < 16; ++r) hv[r] = *(const float4*)&hid[r][j];
#pragma unroll
        for (int jj = 0; jj < 4; ++jj) {
          float2 wv = *(const float2*)(wo + (size_t)(c + j + jj) * 512 + 2 * t);
#pragma unroll
          for (int r = 0; r < 16; ++r) {
            float hc = (&hv[r].x)[jj];
            eo0[r] = fmaf(hc, wv.x, eo0[r]);
            eo1[r] = fmaf(hc, wv.y, eo1[r]);
          }
        }
      }
    }
    {
      float b0 = Bo[(size_t)e * 512 + 2 * t];
      float b1v = Bo[(size_t)e * 512 + 2 * t + 1];
#pragma unroll
      for (int r = 0; r < 16; ++r) { eo0[r] += w * b0; eo1[r] += w * b1v; }
    }
  }
  // --- epilogue: out = x2 + mixed ---
#pragma unroll 1
  for (int r = 0; r < 16; ++r) {
    size_t off = (((size_t)b * 1024) + r0 + r) * 512 + 2 * t;
    float2 xv = *(const float2*)(X2 + off);
    float2 o;
    o.x = xv.x + eo0[r];
    o.y = xv.y + eo1[r];
    *(float2*)(Out + off) = o;
  }
}

// ---------------------------------------------------------------------------
// Launch
// ---------------------------------------------------------------------------
extern "C" void kernel_launch(void* const* d_in, const int* in_sizes, int n_in,
                              void* d_out, int out_size, void* d_ws, size_t ws_size,
                              hipStream_t stream) {
  const float* x        = (const float*)d_in[0];
  const float* scene    = (const float*)d_in[1];
  const float* t_in     = (const float*)d_in[2];
  const float* sn_g     = (const float*)d_in[3];
  const float* sn_b     = (const float*)d_in[4];
  const float* ca_wq    = (const float*)d_in[5];
  const float* ca_bq    = (const float*)d_in[6];
  const float* ca_wk    = (const float*)d_in[7];
  const float* ca_bk    = (const float*)d_in[8];
  const float* ca_wv    = (const float*)d_in[9];
  const float* ca_bv    = (const float*)d_in[10];
  const float* ca_wo    = (const float*)d_in[11];
  const float* ca_bo    = (const float*)d_in[12];
  const float* sa_wq    = (const float*)d_in[13];
  const float* sa_bq    = (const float*)d_in[14];
  const float* sa_wk    = (const float*)d_in[15];
  const float* sa_bk    = (const float*)d_in[16];
  const float* sa_wv    = (const float*)d_in[17];
  const float* sa_bv    = (const float*)d_in[18];
  const float* sa_wo    = (const float*)d_in[19];
  const float* sa_bo    = (const float*)d_in[20];
  const float* ne_w1    = (const float*)d_in[21];
  const float* ne_b1    = (const float*)d_in[22];
  const float* ne_w2    = (const float*)d_in[23];
  const float* ne_b2    = (const float*)d_in[24];
  const float* ncsa_w   = (const float*)d_in[25];
  const float* ncsa_b   = (const float*)d_in[26];
  const float* moe_w    = (const float*)d_in[27];
  const float* moe_b    = (const float*)d_in[28];
  const float* router_w = (const float*)d_in[29];
  const float* fc_in_w  = (const float*)d_in[30];
  const float* fc_in_b  = (const float*)d_in[31];
  const float* fc_out_w = (const float*)d_in[32];
  const float* fc_out_b = (const float*)d_in[33];
  float* out = (float*)d_out;

  // workspace layout: small header (<1MB) + 4 x 16MB activation buffers = 65MB
  float* ncsa_mod = (float*)d_ws;            // [8,1024]
  float* moe_mod  = ncsa_mod + 8 * 1024;     // [8,1024]
  float* tw       = moe_mod + 8 * 1024;      // [8,2]
  int*   ti       = (int*)(tw + 16);         // [8,2]
  char*  base     = (char*)d_ws + (1 << 20);
  float* bufA = (float*)base;                // x_in / attn-out   [8,1024,512]
  float* bufB = bufA + (1 << 22);            // q / x2
  float* bufC = bufB + (1 << 22);            // k
  float* bufD = bufC + (1 << 22);            // v
  float* x1   = out;                         // x1 lives in d_out until MoE overwrites

  const int MBL = B_ * L_;   // 8192
  const int MSC = B_ * NS_;  // 4096

  // 1) noise embed + mods + router
  noise_kernel<<<dim3(B_), dim3(256), 0, stream>>>(
      t_in, ne_w1, ne_b1, ne_w2, ne_b2, ncsa_w, ncsa_b, moe_w, moe_b, router_w,
      ncsa_mod, moe_mod, tw, ti);

  // 2) scene cross-attention
  ln_mod_kernel<<<dim3(MBL), dim3(256), 0, stream>>>(x, sn_g, sn_b, nullptr, bufA);
  gemm_bias<<<dim3(8, 128), dim3(256), 0, stream>>>(bufA, ca_wq, ca_bq, nullptr, bufB, MBL, 512, 512);
  gemm_bias<<<dim3(8, 64), dim3(256), 0, stream>>>(scene, ca_wk, ca_bk, nullptr, bufC, MSC, 512, 512);
  gemm_bias<<<dim3(8, 64), dim3(256), 0, stream>>>(scene, ca_wv, ca_bv, nullptr, bufD, MSC, 512, 512);
  attn_kernel<<<dim3(L_, NH_, B_), dim3(256), 0, stream>>>(bufB, bufC, bufD, bufA, NS_);
  gemm_bias<<<dim3(8, 128), dim3(256), 0, stream>>>(bufA, ca_wo, ca_bo, x, x1, MBL, 512, 512);

  // 3) noise-conditioned self-attention (AdaLN)
  ln_mod_kernel<<<dim3(MBL), dim3(256), 0, stream>>>(x1, nullptr, nullptr, ncsa_mod, bufA);
  gemm_bias<<<dim3(8, 128), dim3(256), 0, stream>>>(bufA, sa_wq, sa_bq, nullptr, bufB, MBL, 512, 512);
  gemm_bias<<<dim3(8, 128), dim3(256), 0, stream>>>(bufA, sa_wk, sa_bk, nullptr, bufC, MBL, 512, 512);
  gemm_bias<<<dim3(8, 128), dim3(256), 0, stream>>>(bufA, sa_wv, sa_bv, nullptr, bufD, MBL, 512, 512);
  attn_kernel<<<dim3(L_, NH_, B_), dim3(256), 0, stream>>>(bufB, bufC, bufD, bufA, L_);
  gemm_bias<<<dim3(8, 128), dim3(256), 0, stream>>>(bufA, sa_wo, sa_bo, x1, bufB, MBL, 512, 512); // x2 -> bufB

  // 4) fused MoE + residual -> out
  moe_kernel<<<dim3(L_ / 16, B_), dim3(256), 0, stream>>>(
      bufB, moe_mod, tw, ti, fc_in_w, fc_in_b, fc_out_w, fc_out_b, out);
}

// Round 3
// 4069.522 us; speedup vs baseline: 3.4568x; 3.4568x over previous
//
#include <hip/hip_runtime.h>
#include <math.h>

// Problem constants
#define B_   8
#define L_   1024
#define NS_  512
#define D_   512
#define NH_  8
#define HD_  64
#define DN_  256
#define E_   8
#define K_   2
#define HE_  2048
#define EPS_ 1e-5f

// ---------------------------------------------------------------------------
// Kernel 1: noise embedding + AdaLN modulation vectors + router top-2
// grid: (B), block: 256
// ---------------------------------------------------------------------------
__global__ __launch_bounds__(256) void noise_kernel(
    const float* __restrict__ t_in,
    const float* __restrict__ w1, const float* __restrict__ b1,
    const float* __restrict__ w2, const float* __restrict__ b2,
    const float* __restrict__ ncsa_w, const float* __restrict__ ncsa_b,
    const float* __restrict__ moe_w, const float* __restrict__ moe_b,
    const float* __restrict__ rw,
    float* __restrict__ ncsa_mod, float* __restrict__ moe_mod,
    float* __restrict__ tw_out, int* __restrict__ ti_out)
{
  const int b = blockIdx.x;
  const int t = threadIdx.x;
  __shared__ float temb[512];
  __shared__ float h1[256];
  __shared__ float ncs[256];
  const float tv = t_in[b];
  {
    float fr = __expf(-logf(10000.0f) * (float)t / 255.0f);
    float ang = tv * fr;
    temb[t] = cosf(ang);
    temb[256 + t] = sinf(ang);
  }
  __syncthreads();
  {
    float s = b1[t];
    for (int i = 0; i < 512; ++i) s += temb[i] * w1[i * 256 + t];
    h1[t] = s / (1.0f + __expf(-s));  // silu
  }
  __syncthreads();
  {
    float s = b2[t];
    for (int i = 0; i < 256; ++i) s += h1[i] * w2[i * 256 + t];
    ncs[t] = s;
  }
  __syncthreads();
  for (int m = t; m < 1024; m += 256) {
    float s1 = ncsa_b[m], s2 = moe_b[m];
    for (int i = 0; i < 256; ++i) {
      float v = ncs[i];
      s1 += v * ncsa_w[i * 1024 + m];
      s2 += v * moe_w[i * 1024 + m];
    }
    ncsa_mod[b * 1024 + m] = s1;
    moe_mod[b * 1024 + m] = s2;
  }
  if (t == 0) {
    float lg[8];
    for (int e = 0; e < 8; ++e) {
      float s = 0.f;
      for (int i = 0; i < 256; ++i) s += ncs[i] * rw[i * 8 + e];
      lg[e] = s;
    }
    float mx = lg[0];
    for (int e = 1; e < 8; ++e) mx = fmaxf(mx, lg[e]);
    float z = 0.f, p[8];
    for (int e = 0; e < 8; ++e) { p[e] = __expf(lg[e] - mx); z += p[e]; }
    for (int e = 0; e < 8; ++e) p[e] /= z;
    int i0 = 0;
    for (int e = 1; e < 8; ++e) if (p[e] > p[i0]) i0 = e;
    int i1 = (i0 == 0) ? 1 : 0;
    for (int e = 0; e < 8; ++e) if (e != i0 && p[e] > p[i1]) i1 = e;
    float s01 = fmaxf(p[i0] + p[i1], 1e-8f);
    tw_out[b * 2 + 0] = p[i0] / s01;
    tw_out[b * 2 + 1] = p[i1] / s01;
    ti_out[b * 2 + 0] = i0;
    ti_out[b * 2 + 1] = i1;
  }
}

// ---------------------------------------------------------------------------
// Kernel 2: LayerNorm + modulation.
// ---------------------------------------------------------------------------
__global__ __launch_bounds__(256) void ln_mod_kernel(
    const float* __restrict__ X, const float* __restrict__ gvec,
    const float* __restrict__ bvec, const float* __restrict__ mod,
    float* __restrict__ Y)
{
  const int row = blockIdx.x;
  const int b = row >> 10;
  const int t = threadIdx.x;
  const float* xr = X + (size_t)row * 512;
  float2 v = *(const float2*)(xr + t * 2);
  float s = v.x + v.y;
  float q = v.x * v.x + v.y * v.y;
#pragma unroll
  for (int off = 32; off > 0; off >>= 1) {
    s += __shfl_down(s, off, 64);
    q += __shfl_down(q, off, 64);
  }
  __shared__ float ws_[4], wq_[4], smu[1], sinv[1];
  if ((t & 63) == 0) { ws_[t >> 6] = s; wq_[t >> 6] = q; }
  __syncthreads();
  if (t == 0) {
    float S = ws_[0] + ws_[1] + ws_[2] + ws_[3];
    float Q = wq_[0] + wq_[1] + wq_[2] + wq_[3];
    float mu = S * (1.0f / 512.0f);
    float var = Q * (1.0f / 512.0f) - mu * mu;
    smu[0] = mu;
    sinv[0] = rsqrtf(var + EPS_);
  }
  __syncthreads();
  const float mu = smu[0], inv = sinv[0];
  const int d0 = t * 2;
  float scx, scy, shx, shy;
  if (mod) {
    const float* mrow = mod + (size_t)b * 1024;
    scx = 1.0f + mrow[512 + d0]; scy = 1.0f + mrow[512 + d0 + 1];
    shx = mrow[d0];              shy = mrow[d0 + 1];
  } else {
    scx = gvec[d0]; scy = gvec[d0 + 1];
    shx = bvec[d0]; shy = bvec[d0 + 1];
  }
  float2 o;
  o.x = (v.x - mu) * inv * scx + shx;
  o.y = (v.y - mu) * inv * scy + shy;
  *(float2*)(Y + (size_t)row * 512 + d0) = o;
}

// ---------------------------------------------------------------------------
// Kernel 3: generic fp32 GEMM  C[M,N] = A[M,Kd] @ W[Kd,N] + bias (+ resid)
// ---------------------------------------------------------------------------
__global__ __launch_bounds__(256) void gemm_bias(
    const float* __restrict__ A, const float* __restrict__ W,
    const float* __restrict__ bias, const float* __restrict__ resid,
    float* __restrict__ C, int M, int Kd, int N)
{
  __shared__ float As[16][68];
  __shared__ float Ws[16][64];
  const int t = threadIdx.x;
  const int tx = t & 15, ty = t >> 4;
  const int bm = blockIdx.y * 64;
  const int bn = blockIdx.x * 64;
  float acc[4][4] = {{0.f}};
  for (int k0 = 0; k0 < Kd; k0 += 16) {
    {
      int r = t >> 2, c = (t & 3) * 4;
      float4 av = *(const float4*)(A + (size_t)(bm + r) * Kd + k0 + c);
      As[c + 0][r] = av.x;
      As[c + 1][r] = av.y;
      As[c + 2][r] = av.z;
      As[c + 3][r] = av.w;
    }
    {
      int kr = t >> 4, c = (t & 15) * 4;
      *(float4*)&Ws[kr][c] = *(const float4*)(W + (size_t)(k0 + kr) * N + bn + c);
    }
    __syncthreads();
#pragma unroll
    for (int kk = 0; kk < 16; ++kk) {
      float4 a4 = *(const float4*)&As[kk][ty * 4];
      float4 b4 = *(const float4*)&Ws[kk][tx * 4];
      float av[4] = {a4.x, a4.y, a4.z, a4.w};
      float bv[4] = {b4.x, b4.y, b4.z, b4.w};
#pragma unroll
      for (int i = 0; i < 4; ++i)
#pragma unroll
        for (int j = 0; j < 4; ++j) acc[i][j] = fmaf(av[i], bv[j], acc[i][j]);
    }
    __syncthreads();
  }
  float4 bb = *(const float4*)(bias + bn + tx * 4);
#pragma unroll
  for (int i = 0; i < 4; ++i) {
    size_t row = (size_t)(bm + ty * 4 + i);
    float4 o;
    o.x = acc[i][0] + bb.x;
    o.y = acc[i][1] + bb.y;
    o.z = acc[i][2] + bb.z;
    o.w = acc[i][3] + bb.w;
    if (resid) {
      float4 rv = *(const float4*)(resid + row * N + bn + tx * 4);
      o.x += rv.x; o.y += rv.y; o.z += rv.z; o.w += rv.w;
    }
    *(float4*)(C + row * N + bn + tx * 4) = o;
  }
}

// ---------------------------------------------------------------------------
// Kernel 4: flash attention.  Q:[B,1024,512]  K,V:[B,Lk,512]
// grid: (1024/256, NH, B), block 256 = 4 waves.
// Each LANE owns one query: q-row (scaled) in 64 VGPRs, acc in 64 VGPRs,
// online-softmax (m,l) per lane -> no cross-lane reductions at all.
// All 4 waves share double-buffered 64-key K/V LDS tiles (64 KB), staged
// async via global_load_lds width=16.  Inner loop: broadcast ds_read_b128
// (all lanes same addr, conflict-free) feeding v_fma streams -> VALU-bound.
// ---------------------------------------------------------------------------
#define GL2LDS(g, l) __builtin_amdgcn_global_load_lds( \
    (const __attribute__((address_space(1))) unsigned int*)(g), \
    (__attribute__((address_space(3))) unsigned int*)(l), 16, 0, 0)

__global__ __launch_bounds__(256, 1) void fattn_kernel(
    const float* __restrict__ Q, const float* __restrict__ Kmat,
    const float* __restrict__ V, float* __restrict__ O, int Lk)
{
  __shared__ float Ks[2][64][64];
  __shared__ float Vs[2][64][64];
  const int t = threadIdx.x;
  const int w = t >> 6, lane = t & 63;
  const int h = blockIdx.y, b = blockIdx.z;
  const int qidx = blockIdx.x * 256 + w * 64 + lane;
  const size_t hoff = (size_t)h * 64;

  // q row -> regs, fold in 1/sqrt(64) score scale
  float qv[64];
  {
    const float* qp = Q + ((size_t)b * 1024 + qidx) * 512 + hoff;
#pragma unroll
    for (int d = 0; d < 64; d += 4) {
      float4 v4 = *(const float4*)(qp + d);
      qv[d + 0] = v4.x * 0.125f;
      qv[d + 1] = v4.y * 0.125f;
      qv[d + 2] = v4.z * 0.125f;
      qv[d + 3] = v4.w * 0.125f;
    }
  }
  const float* Kb = Kmat + (size_t)b * Lk * 512 + hoff;
  const float* Vb = V + (size_t)b * Lk * 512 + hoff;

  // async stage of one 64-key chunk into buffer bi (wave w stages rows w*16..)
  auto stage = [&](int bi, int k0) {
#pragma unroll
    for (int j = 0; j < 4; ++j) {
      const int fidx = w * 1024 + j * 256 + lane * 4;  // float idx in 64x64 tile
      const int row = fidx >> 6, col = fidx & 63;
      GL2LDS(Kb + (size_t)(k0 + row) * 512 + col, &Ks[bi][0][0] + (w * 1024 + j * 256));
      GL2LDS(Vb + (size_t)(k0 + row) * 512 + col, &Vs[bi][0][0] + (w * 1024 + j * 256));
    }
  };

  float acc[64];
#pragma unroll
  for (int d = 0; d < 64; ++d) acc[d] = 0.f;
  float m = -1e30f, lsum = 0.f;

  const int nch = Lk >> 6;
  stage(0, 0);
  __syncthreads();
  for (int c = 0; c < nch; ++c) {
    const int bi = c & 1;
    if (c + 1 < nch) stage(bi ^ 1, (c + 1) << 6);  // async, lands during compute
#pragma unroll 1
    for (int s0 = 0; s0 < 64; s0 += 16) {
      float sc[16];
#pragma unroll
      for (int kk = 0; kk < 16; ++kk) {
        const float* kr = &Ks[bi][s0 + kk][0];
        float p0 = 0.f, p1 = 0.f, p2 = 0.f, p3 = 0.f;
#pragma unroll
        for (int d = 0; d < 64; d += 4) {
          float4 k4 = *(const float4*)(kr + d);  // broadcast read
          p0 = fmaf(qv[d + 0], k4.x, p0);
          p1 = fmaf(qv[d + 1], k4.y, p1);
          p2 = fmaf(qv[d + 2], k4.z, p2);
          p3 = fmaf(qv[d + 3], k4.w, p3);
        }
        sc[kk] = (p0 + p1) + (p2 + p3);
      }
      float cm = sc[0];
#pragma unroll
      for (int kk = 1; kk < 16; ++kk) cm = fmaxf(cm, sc[kk]);
      const float mn = fmaxf(m, cm);
      const float corr = __expf(m - mn);
      m = mn;
      lsum *= corr;
#pragma unroll
      for (int d = 0; d < 64; ++d) acc[d] *= corr;
#pragma unroll
      for (int kk = 0; kk < 16; ++kk) {
        sc[kk] = __expf(sc[kk] - m);
        lsum += sc[kk];
      }
#pragma unroll
      for (int kk = 0; kk < 16; ++kk) {
        const float* vr = &Vs[bi][s0 + kk][0];
        const float e = sc[kk];
#pragma unroll
        for (int d = 0; d < 64; d += 4) {
          float4 v4 = *(const float4*)(vr + d);  // broadcast read
          acc[d + 0] = fmaf(e, v4.x, acc[d + 0]);
          acc[d + 1] = fmaf(e, v4.y, acc[d + 1]);
          acc[d + 2] = fmaf(e, v4.z, acc[d + 2]);
          acc[d + 3] = fmaf(e, v4.w, acc[d + 3]);
        }
      }
    }
    __syncthreads();  // drains prefetch vmcnt + protects buffer reuse
  }
  const float inv = 1.0f / lsum;
  float* op = O + ((size_t)b * 1024 + qidx) * 512 + hoff;
#pragma unroll
  for (int d = 0; d < 64; d += 4) {
    float4 o;
    o.x = acc[d + 0] * inv;
    o.y = acc[d + 1] * inv;
    o.z = acc[d + 2] * inv;
    o.w = acc[d + 3] * inv;
    *(float4*)(op + d) = o;
  }
}

// ---------------------------------------------------------------------------
// Kernel 5: fused MoE (unchanged from R0)
// ---------------------------------------------------------------------------
__global__ __launch_bounds__(256, 2) void moe_kernel(
    const float* __restrict__ X2, const float* __restrict__ mod,
    const float* __restrict__ tw, const int* __restrict__ ti,
    const float* __restrict__ Wi, const float* __restrict__ Bi,
    const float* __restrict__ Wo, const float* __restrict__ Bo,
    float* __restrict__ Out)
{
  const int b = blockIdx.y;
  const int r0 = blockIdx.x * 16;
  const int t = threadIdx.x;
  __shared__ float xs[16][516];
  __shared__ float hid[16][256];
  __shared__ float redS[16][16];
  __shared__ float redQ[16][16];
  __shared__ float rmu[16], rinv[16];

  for (int idx = t; idx < 16 * 512; idx += 256) {
    int r = idx >> 9, d = idx & 511;
    xs[r][d] = X2[(((size_t)b * 1024) + r0 + r) * 512 + d];
  }
  __syncthreads();
  const int rr = t >> 4, li = t & 15;
  {
    float s = 0.f, q = 0.f;
    for (int j = 0; j < 32; ++j) {
      float v = xs[rr][li * 32 + j];
      s += v; q += v * v;
    }
    redS[rr][li] = s; redQ[rr][li] = q;
  }
  __syncthreads();
  if (t < 16) {
    float s = 0.f, q = 0.f;
    for (int i = 0; i < 16; ++i) { s += redS[t][i]; q += redQ[t][i]; }
    float mu = s * (1.0f / 512.0f);
    float var = q * (1.0f / 512.0f) - mu * mu;
    rmu[t] = mu;
    rinv[t] = rsqrtf(var + EPS_);
  }
  __syncthreads();
  {
    float mu = rmu[rr], inv = rinv[rr];
    const float* mrow = mod + (size_t)b * 1024;
    for (int j = 0; j < 32; ++j) {
      int d = li * 32 + j;
      float v = (xs[rr][d] - mu) * inv;
      xs[rr][d] = v * (1.0f + mrow[512 + d]) + mrow[d];
    }
  }
  __syncthreads();

  float eo0[16], eo1[16];
#pragma unroll
  for (int r = 0; r < 16; ++r) { eo0[r] = 0.f; eo1[r] = 0.f; }

  for (int k = 0; k < 2; ++k) {
    const int e = ti[b * 2 + k];
    const float w = tw[b * 2 + k];
    const float* wi = Wi + (size_t)e * 512 * 4096;
    const float* wo = Wo + (size_t)e * 2048 * 512;
    const float* bi = Bi + (size_t)e * 4096;
#pragma unroll 1
    for (int c = 0; c < 2048; c += 256) {
      float vacc[16], gacc[16];
      const float bv = bi[c + t], bg = bi[2048 + c + t];
#pragma unroll
      for (int r = 0; r < 16; ++r) { vacc[r] = bv; gacc[r] = bg; }
#pragma unroll 1
      for (int d = 0; d < 512; d += 4) {
        float4 xv[16];
#pragma unroll
        for (int r = 0; r < 16; ++r) xv[r] = *(const float4*)&xs[r][d];
#pragma unroll
        for (int dd = 0; dd < 4; ++dd) {
          float wv = wi[(size_t)(d + dd) * 4096 + c + t];
          float wg = wi[(size_t)(d + dd) * 4096 + 2048 + c + t];
#pragma unroll
          for (int r = 0; r < 16; ++r) {
            float xc = (&xv[r].x)[dd];
            vacc[r] = fmaf(xc, wv, vacc[r]);
            gacc[r] = fmaf(xc, wg, gacc[r]);
          }
        }
      }
      __syncthreads();
#pragma unroll
      for (int r = 0; r < 16; ++r) {
        float g = gacc[r];
        float hv = vacc[r] * (g / (1.0f + __expf(-g)));
        hid[r][t] = w * hv;
      }
      __syncthreads();
#pragma unroll 1
      for (int j = 0; j < 256; j += 4) {
        float4 hv[16];
#pragma unroll
        for (int r = 0; r < 16; ++r) hv[r] = *(const float4*)&hid[r][j];
#pragma unroll
        for (int jj = 0; jj < 4; ++jj) {
          float2 wv = *(const float2*)(wo + (size_t)(c + j + jj) * 512 + 2 * t);
#pragma unroll
          for (int r = 0; r < 16; ++r) {
            float hc = (&hv[r].x)[jj];
            eo0[r] = fmaf(hc, wv.x, eo0[r]);
            eo1[r] = fmaf(hc, wv.y, eo1[r]);
          }
        }
      }
    }
    {
      float b0 = Bo[(size_t)e * 512 + 2 * t];
      float b1v = Bo[(size_t)e * 512 + 2 * t + 1];
#pragma unroll
      for (int r = 0; r < 16; ++r) { eo0[r] += w * b0; eo1[r] += w * b1v; }
    }
  }
#pragma unroll 1
  for (int r = 0; r < 16; ++r) {
    size_t off = (((size_t)b * 1024) + r0 + r) * 512 + 2 * t;
    float2 xv = *(const float2*)(X2 + off);
    float2 o;
    o.x = xv.x + eo0[r];
    o.y = xv.y + eo1[r];
    *(float2*)(Out + off) = o;
  }
}

// ---------------------------------------------------------------------------
// Launch
// ---------------------------------------------------------------------------
extern "C" void kernel_launch(void* const* d_in, const int* in_sizes, int n_in,
                              void* d_out, int out_size, void* d_ws, size_t ws_size,
                              hipStream_t stream) {
  const float* x        = (const float*)d_in[0];
  const float* scene    = (const float*)d_in[1];
  const float* t_in     = (const float*)d_in[2];
  const float* sn_g     = (const float*)d_in[3];
  const float* sn_b     = (const float*)d_in[4];
  const float* ca_wq    = (const float*)d_in[5];
  const float* ca_bq    = (const float*)d_in[6];
  const float* ca_wk    = (const float*)d_in[7];
  const float* ca_bk    = (const float*)d_in[8];
  const float* ca_wv    = (const float*)d_in[9];
  const float* ca_bv    = (const float*)d_in[10];
  const float* ca_wo    = (const float*)d_in[11];
  const float* ca_bo    = (const float*)d_in[12];
  const float* sa_wq    = (const float*)d_in[13];
  const float* sa_bq    = (const float*)d_in[14];
  const float* sa_wk    = (const float*)d_in[15];
  const float* sa_bk    = (const float*)d_in[16];
  const float* sa_wv    = (const float*)d_in[17];
  const float* sa_bv    = (const float*)d_in[18];
  const float* sa_wo    = (const float*)d_in[19];
  const float* sa_bo    = (const float*)d_in[20];
  const float* ne_w1    = (const float*)d_in[21];
  const float* ne_b1    = (const float*)d_in[22];
  const float* ne_w2    = (const float*)d_in[23];
  const float* ne_b2    = (const float*)d_in[24];
  const float* ncsa_w   = (const float*)d_in[25];
  const float* ncsa_b   = (const float*)d_in[26];
  const float* moe_w    = (const float*)d_in[27];
  const float* moe_b    = (const float*)d_in[28];
  const float* router_w = (const float*)d_in[29];
  const float* fc_in_w  = (const float*)d_in[30];
  const float* fc_in_b  = (const float*)d_in[31];
  const float* fc_out_w = (const float*)d_in[32];
  const float* fc_out_b = (const float*)d_in[33];
  float* out = (float*)d_out;

  float* ncsa_mod = (float*)d_ws;
  float* moe_mod  = ncsa_mod + 8 * 1024;
  float* tw       = moe_mod + 8 * 1024;
  int*   ti       = (int*)(tw + 16);
  char*  base     = (char*)d_ws + (1 << 20);
  float* bufA = (float*)base;
  float* bufB = bufA + (1 << 22);
  float* bufC = bufB + (1 << 22);
  float* bufD = bufC + (1 << 22);
  float* x1   = out;

  const int MBL = B_ * L_;   // 8192
  const int MSC = B_ * NS_;  // 4096

  noise_kernel<<<dim3(B_), dim3(256), 0, stream>>>(
      t_in, ne_w1, ne_b1, ne_w2, ne_b2, ncsa_w, ncsa_b, moe_w, moe_b, router_w,
      ncsa_mod, moe_mod, tw, ti);

  // scene cross-attention
  ln_mod_kernel<<<dim3(MBL), dim3(256), 0, stream>>>(x, sn_g, sn_b, nullptr, bufA);
  gemm_bias<<<dim3(8, 128), dim3(256), 0, stream>>>(bufA, ca_wq, ca_bq, nullptr, bufB, MBL, 512, 512);
  gemm_bias<<<dim3(8, 64), dim3(256), 0, stream>>>(scene, ca_wk, ca_bk, nullptr, bufC, MSC, 512, 512);
  gemm_bias<<<dim3(8, 64), dim3(256), 0, stream>>>(scene, ca_wv, ca_bv, nullptr, bufD, MSC, 512, 512);
  fattn_kernel<<<dim3(4, NH_, B_), dim3(256), 0, stream>>>(bufB, bufC, bufD, bufA, NS_);
  gemm_bias<<<dim3(8, 128), dim3(256), 0, stream>>>(bufA, ca_wo, ca_bo, x, x1, MBL, 512, 512);

  // noise-conditioned self-attention (AdaLN)
  ln_mod_kernel<<<dim3(MBL), dim3(256), 0, stream>>>(x1, nullptr, nullptr, ncsa_mod, bufA);
  gemm_bias<<<dim3(8, 128), dim3(256), 0, stream>>>(bufA, sa_wq, sa_bq, nullptr, bufB, MBL, 512, 512);
  gemm_bias<<<dim3(8, 128), dim3(256), 0, stream>>>(bufA, sa_wk, sa_bk, nullptr, bufC, MBL, 512, 512);
  gemm_bias<<<dim3(8, 128), dim3(256), 0, stream>>>(bufA, sa_wv, sa_bv, nullptr, bufD, MBL, 512, 512);
  fattn_kernel<<<dim3(4, NH_, B_), dim3(256), 0, stream>>>(bufB, bufC, bufD, bufA, L_);
  gemm_bias<<<dim3(8, 128), dim3(256), 0, stream>>>(bufA, sa_wo, sa_bo, x1, bufB, MBL, 512, 512);

  // fused MoE + residual -> out
  moe_kernel<<<dim3(L_ / 16, B_), dim3(256), 0, stream>>>(
      bufB, moe_mod, tw, ti, fc_in_w, fc_in_b, fc_out_w, fc_out_b, out);
}

// Round 5
// 1616.185 us; speedup vs baseline: 8.7040x; 2.5180x over previous
//
#include <hip/hip_runtime.h>
#include <math.h>

typedef unsigned short ushort_t;
typedef __attribute__((ext_vector_type(8))) short short8;
typedef __attribute__((ext_vector_type(4))) float f32x4;

#define B_   8
#define L_   1024
#define NS_  512
#define D_   512
#define NH_  8
#define HE_  2048
#define EPS_ 1e-5f

#define MFMA16(a, b, c) __builtin_amdgcn_mfma_f32_16x16x32_bf16(a, b, c, 0, 0, 0)
#define GL2LDS(g, l) __builtin_amdgcn_global_load_lds( \
    (const __attribute__((address_space(1))) unsigned int*)(g), \
    (__attribute__((address_space(3))) unsigned int*)(l), 16, 0, 0)

__device__ __forceinline__ ushort_t f2bf(float f) {
  unsigned u = __float_as_uint(f);
  unsigned r = (u + 0x7fffu + ((u >> 16) & 1u)) >> 16;
  return (ushort_t)r;
}
__device__ __forceinline__ float bflo(unsigned u) { return __uint_as_float(u << 16); }
__device__ __forceinline__ float bfhi(unsigned u) { return __uint_as_float(u & 0xffff0000u); }

// ---------------------------------------------------------------------------
// Stage a 128x32 bf16 tile (8 KB) from global (row stride ld bf16) into LDS
// via async global_load_lds width=16.  512 chunks; thread t stages 2.
// ---------------------------------------------------------------------------
__device__ __forceinline__ void stage_tile(const ushort_t* __restrict__ g0,
                                           int ld, ushort_t* lds) {
  const int t = threadIdx.x;
  const int w = t >> 6, lane = t & 63;
#pragma unroll
  for (int j = 0; j < 2; ++j) {
    const int c = w * 64 + j * 256 + lane;
    const int row = c >> 2, col = (c & 3) * 8;
    GL2LDS(g0 + (size_t)row * ld + col, lds + (size_t)(w * 64 + j * 256) * 8);
  }
}

// ---------------------------------------------------------------------------
// Kernel 1: noise embedding + AdaLN mods + router top-2.  grid (B), 256 thr.
// ---------------------------------------------------------------------------
__global__ __launch_bounds__(256) void noise_kernel(
    const float* __restrict__ t_in,
    const float* __restrict__ w1, const float* __restrict__ b1,
    const float* __restrict__ w2, const float* __restrict__ b2,
    const float* __restrict__ ncsa_w, const float* __restrict__ ncsa_b,
    const float* __restrict__ moe_w, const float* __restrict__ moe_b,
    const float* __restrict__ rw,
    float* __restrict__ ncsa_mod, float* __restrict__ moe_mod,
    float* __restrict__ tw_out, int* __restrict__ ti_out)
{
  const int b = blockIdx.x;
  const int t = threadIdx.x;
  __shared__ float temb[512];
  __shared__ float h1[256];
  __shared__ float ncs[256];
  const float tv = t_in[b];
  {
    float fr = __expf(-logf(10000.0f) * (float)t / 255.0f);
    float ang = tv * fr;
    temb[t] = cosf(ang);
    temb[256 + t] = sinf(ang);
  }
  __syncthreads();
  {
    float s = b1[t];
    for (int i = 0; i < 512; ++i) s += temb[i] * w1[i * 256 + t];
    h1[t] = s / (1.0f + __expf(-s));
  }
  __syncthreads();
  {
    float s = b2[t];
    for (int i = 0; i < 256; ++i) s += h1[i] * w2[i * 256 + t];
    ncs[t] = s;
  }
  __syncthreads();
  for (int m = t; m < 1024; m += 256) {
    float s1 = ncsa_b[m], s2 = moe_b[m];
    for (int i = 0; i < 256; ++i) {
      float v = ncs[i];
      s1 += v * ncsa_w[i * 1024 + m];
      s2 += v * moe_w[i * 1024 + m];
    }
    ncsa_mod[b * 1024 + m] = s1;
    moe_mod[b * 1024 + m] = s2;
  }
  if (t == 0) {
    float lg[8];
    for (int e = 0; e < 8; ++e) {
      float s = 0.f;
      for (int i = 0; i < 256; ++i) s += ncs[i] * rw[i * 8 + e];
      lg[e] = s;
    }
    float mx = lg[0];
    for (int e = 1; e < 8; ++e) mx = fmaxf(mx, lg[e]);
    float z = 0.f, p[8];
    for (int e = 0; e < 8; ++e) { p[e] = __expf(lg[e] - mx); z += p[e]; }
    for (int e = 0; e < 8; ++e) p[e] /= z;
    int i0 = 0;
    for (int e = 1; e < 8; ++e) if (p[e] > p[i0]) i0 = e;
    int i1 = (i0 == 0) ? 1 : 0;
    for (int e = 0; e < 8; ++e) if (e != i0 && p[e] > p[i1]) i1 = e;
    float s01 = fmaxf(p[i0] + p[i1], 1e-8f);
    tw_out[b * 2 + 0] = p[i0] / s01;
    tw_out[b * 2 + 1] = p[i1] / s01;
    ti_out[b * 2 + 0] = i0;
    ti_out[b * 2 + 1] = i1;
  }
}

// ---------------------------------------------------------------------------
// Kernel 2: LayerNorm + modulation -> bf16 output.
// ---------------------------------------------------------------------------
__global__ __launch_bounds__(256) void ln_mod_kernel(
    const float* __restrict__ X, const float* __restrict__ gvec,
    const float* __restrict__ bvec, const float* __restrict__ mod,
    ushort_t* __restrict__ Y)
{
  const int row = blockIdx.x;
  const int b = row >> 10;
  const int t = threadIdx.x;
  const float* xr = X + (size_t)row * 512;
  float2 v = *(const float2*)(xr + t * 2);
  float s = v.x + v.y;
  float q = v.x * v.x + v.y * v.y;
#pragma unroll
  for (int off = 32; off > 0; off >>= 1) {
    s += __shfl_down(s, off, 64);
    q += __shfl_down(q, off, 64);
  }
  __shared__ float ws_[4], wq_[4], smu[1], sinv[1];
  if ((t & 63) == 0) { ws_[t >> 6] = s; wq_[t >> 6] = q; }
  __syncthreads();
  if (t == 0) {
    float S = ws_[0] + ws_[1] + ws_[2] + ws_[3];
    float Q = wq_[0] + wq_[1] + wq_[2] + wq_[3];
    float mu = S * (1.0f / 512.0f);
    float var = Q * (1.0f / 512.0f) - mu * mu;
    smu[0] = mu;
    sinv[0] = rsqrtf(var + EPS_);
  }
  __syncthreads();
  const float mu = smu[0], inv = sinv[0];
  const int d0 = t * 2;
  float scx, scy, shx, shy;
  if (mod) {
    const float* mrow = mod + (size_t)b * 1024;
    scx = 1.0f + mrow[512 + d0]; scy = 1.0f + mrow[512 + d0 + 1];
    shx = mrow[d0];              shy = mrow[d0 + 1];
  } else {
    scx = gvec[d0]; scy = gvec[d0 + 1];
    shx = bvec[d0]; shy = bvec[d0 + 1];
  }
  float ox = (v.x - mu) * inv * scx + shx;
  float oy = (v.y - mu) * inv * scy + shy;
  unsigned pk = (unsigned)f2bf(ox) | ((unsigned)f2bf(oy) << 16);
  *(unsigned*)(Y + (size_t)row * 512 + d0) = pk;
}

// ---------------------------------------------------------------------------
// Kernel 3a: tiled transpose + fp32->bf16:  in[z][R][C] -> out[z][C][R]
// ---------------------------------------------------------------------------
__global__ __launch_bounds__(256) void transpose_cvt(
    const float* __restrict__ in, ushort_t* __restrict__ out,
    int R, int C, long ibs, long obs)
{
  __shared__ float tile[32][33];
  const float* src = in + (size_t)blockIdx.z * ibs;
  ushort_t* dst = out + (size_t)blockIdx.z * obs;
  const int c0 = blockIdx.x * 32, r0 = blockIdx.y * 32;
  const int tx = threadIdx.x & 31, ty = threadIdx.x >> 5;
  for (int rr = ty; rr < 32; rr += 8)
    tile[rr][tx] = src[(size_t)(r0 + rr) * C + c0 + tx];
  __syncthreads();
  for (int rr = ty; rr < 32; rr += 8)
    dst[(size_t)(c0 + rr) * R + r0 + tx] = f2bf(tile[tx][rr]);
}

// Kernel 3b: plain fp32->bf16 cast (4 elems/thread)
__global__ __launch_bounds__(256) void cvt_bf16(
    const float* __restrict__ in, ushort_t* __restrict__ out)
{
  const int i = (blockIdx.x * 256 + threadIdx.x) * 4;
  float4 v = *(const float4*)(in + i);
  uint2 pk;
  pk.x = (unsigned)f2bf(v.x) | ((unsigned)f2bf(v.y) << 16);
  pk.y = (unsigned)f2bf(v.z) | ((unsigned)f2bf(v.w) << 16);
  *(uint2*)(out + i) = pk;
}

// ---------------------------------------------------------------------------
// Kernel 4: bf16 MFMA GEMM.  C[M,N] = A[M,K](bf16) @ Bt[N,K]^T + bias (+resid)
// out fp32 or bf16.  128x128 tile, BK=32, 4 waves, double-buffered LDS.
// ---------------------------------------------------------------------------
__global__ __launch_bounds__(256) void gemm_bf16(
    const ushort_t* __restrict__ A, const ushort_t* __restrict__ Bt,
    const float* __restrict__ bias, const float* __restrict__ resid,
    void* __restrict__ Cout, int M, int N, int K, int bf16_out)
{
  __shared__ ushort_t As[2][4096];
  __shared__ ushort_t Bs[2][4096];
  const int t = threadIdx.x;
  const int w = t >> 6, lane = t & 63;
  const int quad = lane >> 4, r = lane & 15;
  const int wm = w >> 1, wn = w & 1;
  const int bm = blockIdx.y * 128, bn = blockIdx.x * 128;
  f32x4 acc[4][4];
#pragma unroll
  for (int i = 0; i < 4; ++i)
#pragma unroll
    for (int j = 0; j < 4; ++j) acc[i][j] = (f32x4){0.f, 0.f, 0.f, 0.f};
  const ushort_t* Ab = A + (size_t)bm * K;
  const ushort_t* Bb = Bt + (size_t)bn * K;
  const int NIT = K >> 5;
  stage_tile(Ab, K, As[0]);
  stage_tile(Bb, K, Bs[0]);
  __syncthreads();
  for (int it = 0; it < NIT; ++it) {
    const int cur = it & 1;
    if (it + 1 < NIT) {
      stage_tile(Ab + (it + 1) * 32, K, As[cur ^ 1]);
      stage_tile(Bb + (it + 1) * 32, K, Bs[cur ^ 1]);
    }
    short8 af[4], bfg[4];
#pragma unroll
    for (int i = 0; i < 4; ++i)
      af[i] = *(const short8*)&As[cur][(wm * 64 + i * 16 + r) * 32 + quad * 8];
#pragma unroll
    for (int j = 0; j < 4; ++j)
      bfg[j] = *(const short8*)&Bs[cur][(wn * 64 + j * 16 + r) * 32 + quad * 8];
#pragma unroll
    for (int i = 0; i < 4; ++i)
#pragma unroll
      for (int j = 0; j < 4; ++j)
        acc[i][j] = MFMA16(af[i], bfg[j], acc[i][j]);
    __syncthreads();
  }
  if (bf16_out) {
    ushort_t* Cb = (ushort_t*)Cout;
#pragma unroll
    for (int j = 0; j < 4; ++j) {
      const int col = bn + wn * 64 + j * 16 + r;
      const float bia = bias[col];
#pragma unroll
      for (int i = 0; i < 4; ++i)
#pragma unroll
        for (int reg = 0; reg < 4; ++reg) {
          const int row = bm + wm * 64 + i * 16 + quad * 4 + reg;
          Cb[(size_t)row * N + col] = f2bf(acc[i][j][reg] + bia);
        }
    }
  } else {
    float* Cf = (float*)Cout;
#pragma unroll
    for (int j = 0; j < 4; ++j) {
      const int col = bn + wn * 64 + j * 16 + r;
      const float bia = bias[col];
#pragma unroll
      for (int i = 0; i < 4; ++i)
#pragma unroll
        for (int reg = 0; reg < 4; ++reg) {
          const int row = bm + wm * 64 + i * 16 + quad * 4 + reg;
          float v = acc[i][j][reg] + bia;
          if (resid) v += resid[(size_t)row * N + col];
          Cf[(size_t)row * N + col] = v;
        }
    }
  }
}

// ---------------------------------------------------------------------------
// Kernel 5: flash attention, bf16 Q/K/V in, bf16 out.  grid (4, NH, B), 256.
// Lane owns one query (fp32 math).  bf16->fp32 conversion happens during
// LDS staging (load->cvt->ds_write, double-buffered through registers).
// ---------------------------------------------------------------------------
__global__ __launch_bounds__(256, 1) void fattn_kernel(
    const ushort_t* __restrict__ Q, const ushort_t* __restrict__ Kmat,
    const ushort_t* __restrict__ V, ushort_t* __restrict__ O, int Lk)
{
  __shared__ float Ks[2][64][64];
  __shared__ float Vs[2][64][64];
  const int t = threadIdx.x;
  const int w = t >> 6, lane = t & 63;
  const int h = blockIdx.y, b = blockIdx.z;
  const int qidx = blockIdx.x * 256 + w * 64 + lane;
  const size_t hoff = (size_t)h * 64;

  float qv[64];
  {
    const ushort_t* qp = Q + ((size_t)b * 1024 + qidx) * 512 + hoff;
#pragma unroll
    for (int d = 0; d < 64; d += 8) {
      uint4 p = *(const uint4*)(qp + d);
      qv[d + 0] = bflo(p.x) * 0.125f; qv[d + 1] = bfhi(p.x) * 0.125f;
      qv[d + 2] = bflo(p.y) * 0.125f; qv[d + 3] = bfhi(p.y) * 0.125f;
      qv[d + 4] = bflo(p.z) * 0.125f; qv[d + 5] = bfhi(p.z) * 0.125f;
      qv[d + 6] = bflo(p.w) * 0.125f; qv[d + 7] = bfhi(p.w) * 0.125f;
    }
  }
  const ushort_t* Kb = Kmat + (size_t)b * Lk * 512 + hoff;
  const ushort_t* Vb = V + (size_t)b * Lk * 512 + hoff;
  const int row0 = t >> 3, col0 = (t & 7) * 8;  // chunk t ; chunk t+256 -> row0+32

  uint4 kc[2], vc[2], kn[2], vn[2];
  auto ldtile = [&](int k0, uint4* kp, uint4* vp) {
    kp[0] = *(const uint4*)(Kb + (size_t)(k0 + row0) * 512 + col0);
    kp[1] = *(const uint4*)(Kb + (size_t)(k0 + row0 + 32) * 512 + col0);
    vp[0] = *(const uint4*)(Vb + (size_t)(k0 + row0) * 512 + col0);
    vp[1] = *(const uint4*)(Vb + (size_t)(k0 + row0 + 32) * 512 + col0);
  };
  auto cvtst = [&](float* dst, uint4 p) {
    float4 a = {bflo(p.x), bfhi(p.x), bflo(p.y), bfhi(p.y)};
    float4 c = {bflo(p.z), bfhi(p.z), bflo(p.w), bfhi(p.w)};
    *(float4*)(dst) = a;
    *(float4*)(dst + 4) = c;
  };
  auto sttile = [&](int bi, const uint4* kp, const uint4* vp) {
    cvtst(&Ks[bi][row0][col0], kp[0]);
    cvtst(&Ks[bi][row0 + 32][col0], kp[1]);
    cvtst(&Vs[bi][row0][col0], vp[0]);
    cvtst(&Vs[bi][row0 + 32][col0], vp[1]);
  };

  float acc[64];
#pragma unroll
  for (int d = 0; d < 64; ++d) acc[d] = 0.f;
  float m = -1e30f, lsum = 0.f;

  const int nch = Lk >> 6;
  ldtile(0, kc, vc);
  sttile(0, kc, vc);
  __syncthreads();
  for (int c = 0; c < nch; ++c) {
    const int bi = c & 1;
    if (c + 1 < nch) ldtile((c + 1) << 6, kn, vn);  // loads in flight over compute
#pragma unroll 1
    for (int s0 = 0; s0 < 64; s0 += 16) {
      float sc[16];
#pragma unroll
      for (int kk = 0; kk < 16; ++kk) {
        const float* kr = &Ks[bi][s0 + kk][0];
        float p0 = 0.f, p1 = 0.f, p2 = 0.f, p3 = 0.f;
#pragma unroll
        for (int d = 0; d < 64; d += 4) {
          float4 k4 = *(const float4*)(kr + d);  // broadcast read
          p0 = fmaf(qv[d + 0], k4.x, p0);
          p1 = fmaf(qv[d + 1], k4.y, p1);
          p2 = fmaf(qv[d + 2], k4.z, p2);
          p3 = fmaf(qv[d + 3], k4.w, p3);
        }
        sc[kk] = (p0 + p1) + (p2 + p3);
      }
      float cm = sc[0];
#pragma unroll
      for (int kk = 1; kk < 16; ++kk) cm = fmaxf(cm, sc[kk]);
      const float mn = fmaxf(m, cm);
      const float corr = __expf(m - mn);
      m = mn;
      lsum *= corr;
#pragma unroll
      for (int d = 0; d < 64; ++d) acc[d] *= corr;
#pragma unroll
      for (int kk = 0; kk < 16; ++kk) {
        sc[kk] = __expf(sc[kk] - m);
        lsum += sc[kk];
      }
#pragma unroll
      for (int kk = 0; kk < 16; ++kk) {
        const float* vr = &Vs[bi][s0 + kk][0];
        const float e = sc[kk];
#pragma unroll
        for (int d = 0; d < 64; d += 4) {
          float4 v4 = *(const float4*)(vr + d);  // broadcast read
          acc[d + 0] = fmaf(e, v4.x, acc[d + 0]);
          acc[d + 1] = fmaf(e, v4.y, acc[d + 1]);
          acc[d + 2] = fmaf(e, v4.z, acc[d + 2]);
          acc[d + 3] = fmaf(e, v4.w, acc[d + 3]);
        }
      }
    }
    if (c + 1 < nch) sttile(bi ^ 1, kn, vn);  // write other buffer
    __syncthreads();
  }
  const float inv = 1.0f / lsum;
  ushort_t* op = O + ((size_t)b * 1024 + qidx) * 512 + hoff;
#pragma unroll
  for (int d = 0; d < 64; d += 2) {
    unsigned pk = (unsigned)f2bf(acc[d] * inv) |
                  ((unsigned)f2bf(acc[d + 1] * inv) << 16);
    *(unsigned*)(op + d) = pk;
  }
}

// ---------------------------------------------------------------------------
// Kernel 6: MoE fc_in for ONE expert slot ks.  grid (16, 8, B), 256 thr.
// hid[b][1024][2048] bf16 out (silu-gated, router weight folded in).
// ---------------------------------------------------------------------------
__global__ __launch_bounds__(256) void moe_fcin(
    const ushort_t* __restrict__ Xm, const ushort_t* __restrict__ WiT,
    const float* __restrict__ Bi, const float* __restrict__ tw,
    const int* __restrict__ ti, ushort_t* __restrict__ Hid, int ks)
{
  __shared__ ushort_t As[2][4096];
  __shared__ ushort_t Bv[2][4096];
  __shared__ ushort_t Bg[2][4096];
  const int t = threadIdx.x;
  const int w = t >> 6, lane = t & 63;
  const int quad = lane >> 4, r = lane & 15;
  const int wm = w >> 1, wn = w & 1;
  const int b = blockIdx.z;
  const int e = ti[b * 2 + ks];
  const float wq = tw[b * 2 + ks];
  const int r0 = blockIdx.y * 128, n0 = blockIdx.x * 128;
  const ushort_t* Ab = Xm + ((size_t)b * 1024 + r0) * 512;
  const ushort_t* Wv = WiT + (size_t)e * 4096 * 512 + (size_t)n0 * 512;
  const ushort_t* Wg = Wv + (size_t)2048 * 512;
  f32x4 av[4][4], ag[4][4];
#pragma unroll
  for (int i = 0; i < 4; ++i)
#pragma unroll
    for (int j = 0; j < 4; ++j) {
      av[i][j] = (f32x4){0.f, 0.f, 0.f, 0.f};
      ag[i][j] = (f32x4){0.f, 0.f, 0.f, 0.f};
    }
  stage_tile(Ab, 512, As[0]);
  stage_tile(Wv, 512, Bv[0]);
  stage_tile(Wg, 512, Bg[0]);
  __syncthreads();
  for (int it = 0; it < 16; ++it) {
    const int cur = it & 1;
    if (it + 1 < 16) {
      stage_tile(Ab + (it + 1) * 32, 512, As[cur ^ 1]);
      stage_tile(Wv + (it + 1) * 32, 512, Bv[cur ^ 1]);
      stage_tile(Wg + (it + 1) * 32, 512, Bg[cur ^ 1]);
    }
    short8 af[4], bv[4], bg[4];
#pragma unroll
    for (int i = 0; i < 4; ++i)
      af[i] = *(const short8*)&As[cur][(wm * 64 + i * 16 + r) * 32 + quad * 8];
#pragma unroll
    for (int j = 0; j < 4; ++j) {
      bv[j] = *(const short8*)&Bv[cur][(wn * 64 + j * 16 + r) * 32 + quad * 8];
      bg[j] = *(const short8*)&Bg[cur][(wn * 64 + j * 16 + r) * 32 + quad * 8];
    }
#pragma unroll
    for (int i = 0; i < 4; ++i)
#pragma unroll
      for (int j = 0; j < 4; ++j) {
        av[i][j] = MFMA16(af[i], bv[j], av[i][j]);
        ag[i][j] = MFMA16(af[i], bg[j], ag[i][j]);
      }
    __syncthreads();
  }
  ushort_t* Hb = Hid + (size_t)b * 1024 * 2048;
#pragma unroll
  for (int j = 0; j < 4; ++j) {
    const int col = n0 + wn * 64 + j * 16 + r;
    const float bval = Bi[(size_t)e * 4096 + col];
    const float bgat = Bi[(size_t)e * 4096 + 2048 + col];
#pragma unroll
    for (int i = 0; i < 4; ++i)
#pragma unroll
      for (int reg = 0; reg < 4; ++reg) {
        const int lrow = r0 + wm * 64 + i * 16 + quad * 4 + reg;
        float vv = av[i][j][reg] + bval;
        float gg = ag[i][j][reg] + bgat;
        float hv = vv * (gg / (1.0f + __expf(-gg))) * wq;
        Hb[(size_t)lrow * 2048 + col] = f2bf(hv);
      }
  }
}

// ---------------------------------------------------------------------------
// Kernel 7: MoE fc_out for ONE slot.  grid (4, 8, B), 256 thr.
// first=1: Out = X2 + acc + (tw0*bo_e0 + tw1*bo_e1);  first=0: Out += acc
// (X2 may alias Out: same-thread read-then-write.)
// ---------------------------------------------------------------------------
__global__ __launch_bounds__(256) void moe_fcout(
    const ushort_t* __restrict__ Hid, const ushort_t* __restrict__ WoT,
    const float* __restrict__ Bo, const float* __restrict__ X2,
    const float* __restrict__ tw, const int* __restrict__ ti,
    float* __restrict__ Out, int ks, int first)
{
  __shared__ ushort_t As[2][4096];
  __shared__ ushort_t Bs[2][4096];
  const int t = threadIdx.x;
  const int w = t >> 6, lane = t & 63;
  const int quad = lane >> 4, r = lane & 15;
  const int wm = w >> 1, wn = w & 1;
  const int b = blockIdx.z;
  const int e = ti[b * 2 + ks];
  const int r0 = blockIdx.y * 128, n0 = blockIdx.x * 128;
  f32x4 acc[4][4];
#pragma unroll
  for (int i = 0; i < 4; ++i)
#pragma unroll
    for (int j = 0; j < 4; ++j) acc[i][j] = (f32x4){0.f, 0.f, 0.f, 0.f};
  const ushort_t* Ab = Hid + ((size_t)b * 1024 + r0) * 2048;
  const ushort_t* Bb = WoT + (size_t)e * 512 * 2048 + (size_t)n0 * 2048;
  stage_tile(Ab, 2048, As[0]);
  stage_tile(Bb, 2048, Bs[0]);
  __syncthreads();
  for (int it = 0; it < 64; ++it) {
    const int cur = it & 1;
    if (it + 1 < 64) {
      stage_tile(Ab + (it + 1) * 32, 2048, As[cur ^ 1]);
      stage_tile(Bb + (it + 1) * 32, 2048, Bs[cur ^ 1]);
    }
    short8 af[4], bfg[4];
#pragma unroll
    for (int i = 0; i < 4; ++i)
      af[i] = *(const short8*)&As[cur][(wm * 64 + i * 16 + r) * 32 + quad * 8];
#pragma unroll
    for (int j = 0; j < 4; ++j)
      bfg[j] = *(const short8*)&Bs[cur][(wn * 64 + j * 16 + r) * 32 + quad * 8];
#pragma unroll
    for (int i = 0; i < 4; ++i)
#pragma unroll
      for (int j = 0; j < 4; ++j)
        acc[i][j] = MFMA16(af[i], bfg[j], acc[i][j]);
    __syncthreads();
  }
  const int e0 = ti[b * 2], e1 = ti[b * 2 + 1];
  const float tw0 = tw[b * 2], tw1 = tw[b * 2 + 1];
#pragma unroll
  for (int j = 0; j < 4; ++j) {
    const int col = n0 + wn * 64 + j * 16 + r;
    const float badd = first ? (tw0 * Bo[(size_t)e0 * 512 + col] +
                                tw1 * Bo[(size_t)e1 * 512 + col]) : 0.f;
#pragma unroll
    for (int i = 0; i < 4; ++i)
#pragma unroll
      for (int reg = 0; reg < 4; ++reg) {
        const size_t row = (size_t)b * 1024 + r0 + wm * 64 + i * 16 + quad * 4 + reg;
        const size_t idx = row * 512 + col;
        const float base = first ? X2[idx] : Out[idx];
        Out[idx] = base + acc[i][j][reg] + badd;
      }
  }
}

// ---------------------------------------------------------------------------
// Launch.  Workspace: 93 MiB total (was 164 MB in the failed R4 layout).
// ---------------------------------------------------------------------------
extern "C" void kernel_launch(void* const* d_in, const int* in_sizes, int n_in,
                              void* d_out, int out_size, void* d_ws, size_t ws_size,
                              hipStream_t stream) {
  const float* x        = (const float*)d_in[0];
  const float* scene    = (const float*)d_in[1];
  const float* t_in     = (const float*)d_in[2];
  const float* sn_g     = (const float*)d_in[3];
  const float* sn_b     = (const float*)d_in[4];
  const float* ca_wq    = (const float*)d_in[5];
  const float* ca_bq    = (const float*)d_in[6];
  const float* ca_wk    = (const float*)d_in[7];
  const float* ca_bk    = (const float*)d_in[8];
  const float* ca_wv    = (const float*)d_in[9];
  const float* ca_bv    = (const float*)d_in[10];
  const float* ca_wo    = (const float*)d_in[11];
  const float* ca_bo    = (const float*)d_in[12];
  const float* sa_wq    = (const float*)d_in[13];
  const float* sa_bq    = (const float*)d_in[14];
  const float* sa_wk    = (const float*)d_in[15];
  const float* sa_bk    = (const float*)d_in[16];
  const float* sa_wv    = (const float*)d_in[17];
  const float* sa_bv    = (const float*)d_in[18];
  const float* sa_wo    = (const float*)d_in[19];
  const float* sa_bo    = (const float*)d_in[20];
  const float* ne_w1    = (const float*)d_in[21];
  const float* ne_b1    = (const float*)d_in[22];
  const float* ne_w2    = (const float*)d_in[23];
  const float* ne_b2    = (const float*)d_in[24];
  const float* ncsa_w   = (const float*)d_in[25];
  const float* ncsa_b   = (const float*)d_in[26];
  const float* moe_w    = (const float*)d_in[27];
  const float* moe_b    = (const float*)d_in[28];
  const float* router_w = (const float*)d_in[29];
  const float* fc_in_w  = (const float*)d_in[30];
  const float* fc_in_b  = (const float*)d_in[31];
  const float* fc_out_w = (const float*)d_in[32];
  const float* fc_out_b = (const float*)d_in[33];
  float* out = (float*)d_out;

  // ---- workspace layout (MiB offsets; 93 MiB total) ----
  char* W = (char*)d_ws;
  const size_t MB = 1u << 20;
  float* ncsa_mod = (float*)W;                    // @0: 32 KB
  float* moe_mod  = ncsa_mod + 8192;              // 32 KB
  float* tw       = moe_mod + 8192;
  int*   ti       = (int*)(tw + 16);
  ushort_t* wT      = (ushort_t*)(W + 1 * MB);    // 8 dense W^T, 4 MiB
  ushort_t* fciT    = (ushort_t*)(W + 5 * MB);    // fc_in^T [8][4096][512], 32 MiB
  ushort_t* fcoT    = (ushort_t*)(W + 37 * MB);   // fc_out^T [8][512][2048], 16 MiB
  ushort_t* xin_bf  = (ushort_t*)(W + 53 * MB);   // [8192,512] bf16, 8 MiB
  ushort_t* attn_bf = xin_bf;                     // alias (xin dead when attn written)
  ushort_t* scene_bf= (ushort_t*)(W + 61 * MB);   // [4096,512] bf16, 4 MiB
  ushort_t* qf = (ushort_t*)(W + 65 * MB);        // bf16, 8 MiB each
  ushort_t* kf = (ushort_t*)(W + 73 * MB);
  ushort_t* vf = (ushort_t*)(W + 81 * MB);        // ends 89 MiB
  ushort_t* hid = (ushort_t*)(W + 61 * MB);       // [8][1024][2048] bf16, 32 MiB
                                                  // overlays scene/q/k/v (dead in MoE)
  float* x1 = out;                                // x1 then x2 then final all in d_out

  const int WSZ = 512 * 512;

  noise_kernel<<<dim3(B_), dim3(256), 0, stream>>>(
      t_in, ne_w1, ne_b1, ne_w2, ne_b2, ncsa_w, ncsa_b, moe_w, moe_b, router_w,
      ncsa_mod, moe_mod, tw, ti);

  // weight prep
  transpose_cvt<<<dim3(16, 16, 1), 256, 0, stream>>>(ca_wq, wT + 0 * WSZ, 512, 512, 0, 0);
  transpose_cvt<<<dim3(16, 16, 1), 256, 0, stream>>>(ca_wk, wT + 1 * WSZ, 512, 512, 0, 0);
  transpose_cvt<<<dim3(16, 16, 1), 256, 0, stream>>>(ca_wv, wT + 2 * WSZ, 512, 512, 0, 0);
  transpose_cvt<<<dim3(16, 16, 1), 256, 0, stream>>>(ca_wo, wT + 3 * WSZ, 512, 512, 0, 0);
  transpose_cvt<<<dim3(16, 16, 1), 256, 0, stream>>>(sa_wq, wT + 4 * WSZ, 512, 512, 0, 0);
  transpose_cvt<<<dim3(16, 16, 1), 256, 0, stream>>>(sa_wk, wT + 5 * WSZ, 512, 512, 0, 0);
  transpose_cvt<<<dim3(16, 16, 1), 256, 0, stream>>>(sa_wv, wT + 6 * WSZ, 512, 512, 0, 0);
  transpose_cvt<<<dim3(16, 16, 1), 256, 0, stream>>>(sa_wo, wT + 7 * WSZ, 512, 512, 0, 0);
  transpose_cvt<<<dim3(128, 16, 8), 256, 0, stream>>>(fc_in_w, fciT, 512, 4096,
                                                      (long)512 * 4096, (long)512 * 4096);
  transpose_cvt<<<dim3(16, 64, 8), 256, 0, stream>>>(fc_out_w, fcoT, 2048, 512,
                                                     (long)2048 * 512, (long)2048 * 512);
  cvt_bf16<<<dim3(2048), 256, 0, stream>>>(scene, scene_bf);

  // scene cross-attention
  ln_mod_kernel<<<dim3(8192), 256, 0, stream>>>(x, sn_g, sn_b, nullptr, xin_bf);
  gemm_bf16<<<dim3(4, 64), 256, 0, stream>>>(xin_bf, wT + 0 * WSZ, ca_bq, nullptr, qf, 8192, 512, 512, 1);
  gemm_bf16<<<dim3(4, 32), 256, 0, stream>>>(scene_bf, wT + 1 * WSZ, ca_bk, nullptr, kf, 4096, 512, 512, 1);
  gemm_bf16<<<dim3(4, 32), 256, 0, stream>>>(scene_bf, wT + 2 * WSZ, ca_bv, nullptr, vf, 4096, 512, 512, 1);
  fattn_kernel<<<dim3(4, NH_, B_), 256, 0, stream>>>(qf, kf, vf, attn_bf, NS_);
  gemm_bf16<<<dim3(4, 64), 256, 0, stream>>>(attn_bf, wT + 3 * WSZ, ca_bo, x, x1, 8192, 512, 512, 0);

  // noise-conditioned self-attention (AdaLN)
  ln_mod_kernel<<<dim3(8192), 256, 0, stream>>>(x1, nullptr, nullptr, ncsa_mod, xin_bf);
  gemm_bf16<<<dim3(4, 64), 256, 0, stream>>>(xin_bf, wT + 4 * WSZ, sa_bq, nullptr, qf, 8192, 512, 512, 1);
  gemm_bf16<<<dim3(4, 64), 256, 0, stream>>>(xin_bf, wT + 5 * WSZ, sa_bk, nullptr, kf, 8192, 512, 512, 1);
  gemm_bf16<<<dim3(4, 64), 256, 0, stream>>>(xin_bf, wT + 6 * WSZ, sa_bv, nullptr, vf, 8192, 512, 512, 1);
  fattn_kernel<<<dim3(4, NH_, B_), 256, 0, stream>>>(qf, kf, vf, attn_bf, L_);
  // x2 = x1 + attn@wo  (in-place in d_out: resid==dst, same-thread R/W)
  gemm_bf16<<<dim3(4, 64), 256, 0, stream>>>(attn_bf, wT + 7 * WSZ, sa_bo, out, out, 8192, 512, 512, 0);

  // MoE: AdaLN -> per-slot fc_in/fc_out, accumulating into d_out
  ln_mod_kernel<<<dim3(8192), 256, 0, stream>>>(out, nullptr, nullptr, moe_mod, xin_bf);
  moe_fcin<<<dim3(16, 8, B_), 256, 0, stream>>>(xin_bf, fciT, fc_in_b, tw, ti, hid, 0);
  moe_fcout<<<dim3(4, 8, B_), 256, 0, stream>>>(hid, fcoT, fc_out_b, out, tw, ti, out, 0, 1);
  moe_fcin<<<dim3(16, 8, B_), 256, 0, stream>>>(xin_bf, fciT, fc_in_b, tw, ti, hid, 1);
  moe_fcout<<<dim3(4, 8, B_), 256, 0, stream>>>(hid, fcoT, fc_out_b, out, tw, ti, out, 1, 0);
}

// Round 6
// 891.858 us; speedup vs baseline: 15.7731x; 1.8122x over previous
//
#include <hip/hip_runtime.h>
#include <math.h>

typedef unsigned short ushort_t;
typedef __attribute__((ext_vector_type(8))) short short8;
typedef __attribute__((ext_vector_type(4))) float f32x4;

#define B_   8
#define L_   1024
#define NS_  512
#define D_   512
#define NH_  8
#define HE_  2048
#define EPS_ 1e-5f

#define MFMA16(a, b, c) __builtin_amdgcn_mfma_f32_16x16x32_bf16(a, b, c, 0, 0, 0)
#define GL2LDS(g, l) __builtin_amdgcn_global_load_lds( \
    (const __attribute__((address_space(1))) unsigned int*)(g), \
    (__attribute__((address_space(3))) unsigned int*)(l), 16, 0, 0)

__device__ __forceinline__ ushort_t f2bf(float f) {
  unsigned u = __float_as_uint(f);
  unsigned r = (u + 0x7fffu + ((u >> 16) & 1u)) >> 16;
  return (ushort_t)r;
}

// ---------------------------------------------------------------------------
// Stage a 128x32 bf16 tile (8 KB) from global (row stride ld bf16) into LDS
// via async global_load_lds width=16.  512 chunks; thread t stages 2.
// ---------------------------------------------------------------------------
__device__ __forceinline__ void stage_tile(const ushort_t* __restrict__ g0,
                                           int ld, ushort_t* lds) {
  const int t = threadIdx.x;
  const int w = t >> 6, lane = t & 63;
#pragma unroll
  for (int j = 0; j < 2; ++j) {
    const int c = w * 64 + j * 256 + lane;
    const int row = c >> 2, col = (c & 3) * 8;
    GL2LDS(g0 + (size_t)row * ld + col, lds + (size_t)(w * 64 + j * 256) * 8);
  }
}

// ---------------------------------------------------------------------------
// Kernel 1: noise embedding + AdaLN mods + router top-2.  grid (B), 256 thr.
// ---------------------------------------------------------------------------
__global__ __launch_bounds__(256) void noise_kernel(
    const float* __restrict__ t_in,
    const float* __restrict__ w1, const float* __restrict__ b1,
    const float* __restrict__ w2, const float* __restrict__ b2,
    const float* __restrict__ ncsa_w, const float* __restrict__ ncsa_b,
    const float* __restrict__ moe_w, const float* __restrict__ moe_b,
    const float* __restrict__ rw,
    float* __restrict__ ncsa_mod, float* __restrict__ moe_mod,
    float* __restrict__ tw_out, int* __restrict__ ti_out)
{
  const int b = blockIdx.x;
  const int t = threadIdx.x;
  __shared__ float temb[512];
  __shared__ float h1[256];
  __shared__ float ncs[256];
  const float tv = t_in[b];
  {
    float fr = __expf(-logf(10000.0f) * (float)t / 255.0f);
    float ang = tv * fr;
    temb[t] = cosf(ang);
    temb[256 + t] = sinf(ang);
  }
  __syncthreads();
  {
    float s = b1[t];
    for (int i = 0; i < 512; ++i) s += temb[i] * w1[i * 256 + t];
    h1[t] = s / (1.0f + __expf(-s));
  }
  __syncthreads();
  {
    float s = b2[t];
    for (int i = 0; i < 256; ++i) s += h1[i] * w2[i * 256 + t];
    ncs[t] = s;
  }
  __syncthreads();
  for (int m = t; m < 1024; m += 256) {
    float s1 = ncsa_b[m], s2 = moe_b[m];
    for (int i = 0; i < 256; ++i) {
      float v = ncs[i];
      s1 += v * ncsa_w[i * 1024 + m];
      s2 += v * moe_w[i * 1024 + m];
    }
    ncsa_mod[b * 1024 + m] = s1;
    moe_mod[b * 1024 + m] = s2;
  }
  if (t == 0) {
    float lg[8];
    for (int e = 0; e < 8; ++e) {
      float s = 0.f;
      for (int i = 0; i < 256; ++i) s += ncs[i] * rw[i * 8 + e];
      lg[e] = s;
    }
    float mx = lg[0];
    for (int e = 1; e < 8; ++e) mx = fmaxf(mx, lg[e]);
    float z = 0.f, p[8];
    for (int e = 0; e < 8; ++e) { p[e] = __expf(lg[e] - mx); z += p[e]; }
    for (int e = 0; e < 8; ++e) p[e] /= z;
    int i0 = 0;
    for (int e = 1; e < 8; ++e) if (p[e] > p[i0]) i0 = e;
    int i1 = (i0 == 0) ? 1 : 0;
    for (int e = 0; e < 8; ++e) if (e != i0 && p[e] > p[i1]) i1 = e;
    float s01 = fmaxf(p[i0] + p[i1], 1e-8f);
    tw_out[b * 2 + 0] = p[i0] / s01;
    tw_out[b * 2 + 1] = p[i1] / s01;
    ti_out[b * 2 + 0] = i0;
    ti_out[b * 2 + 1] = i1;
  }
}

// ---------------------------------------------------------------------------
// Kernel 2: LayerNorm + modulation -> bf16 output.
// ---------------------------------------------------------------------------
__global__ __launch_bounds__(256) void ln_mod_kernel(
    const float* __restrict__ X, const float* __restrict__ gvec,
    const float* __restrict__ bvec, const float* __restrict__ mod,
    ushort_t* __restrict__ Y)
{
  const int row = blockIdx.x;
  const int b = row >> 10;
  const int t = threadIdx.x;
  const float* xr = X + (size_t)row * 512;
  float2 v = *(const float2*)(xr + t * 2);
  float s = v.x + v.y;
  float q = v.x * v.x + v.y * v.y;
#pragma unroll
  for (int off = 32; off > 0; off >>= 1) {
    s += __shfl_down(s, off, 64);
    q += __shfl_down(q, off, 64);
  }
  __shared__ float ws_[4], wq_[4], smu[1], sinv[1];
  if ((t & 63) == 0) { ws_[t >> 6] = s; wq_[t >> 6] = q; }
  __syncthreads();
  if (t == 0) {
    float S = ws_[0] + ws_[1] + ws_[2] + ws_[3];
    float Q = wq_[0] + wq_[1] + wq_[2] + wq_[3];
    float mu = S * (1.0f / 512.0f);
    float var = Q * (1.0f / 512.0f) - mu * mu;
    smu[0] = mu;
    sinv[0] = rsqrtf(var + EPS_);
  }
  __syncthreads();
  const float mu = smu[0], inv = sinv[0];
  const int d0 = t * 2;
  float scx, scy, shx, shy;
  if (mod) {
    const float* mrow = mod + (size_t)b * 1024;
    scx = 1.0f + mrow[512 + d0]; scy = 1.0f + mrow[512 + d0 + 1];
    shx = mrow[d0];              shy = mrow[d0 + 1];
  } else {
    scx = gvec[d0]; scy = gvec[d0 + 1];
    shx = bvec[d0]; shy = bvec[d0 + 1];
  }
  float ox = (v.x - mu) * inv * scx + shx;
  float oy = (v.y - mu) * inv * scy + shy;
  unsigned pk = (unsigned)f2bf(ox) | ((unsigned)f2bf(oy) << 16);
  *(unsigned*)(Y + (size_t)row * 512 + d0) = pk;
}

// ---------------------------------------------------------------------------
// Kernel 3a: tiled transpose + fp32->bf16:  in[z][R][C] -> out[z][C][R]
// ---------------------------------------------------------------------------
__global__ __launch_bounds__(256) void transpose_cvt(
    const float* __restrict__ in, ushort_t* __restrict__ out,
    int R, int C, long ibs, long obs)
{
  __shared__ float tile[32][33];
  const float* src = in + (size_t)blockIdx.z * ibs;
  ushort_t* dst = out + (size_t)blockIdx.z * obs;
  const int c0 = blockIdx.x * 32, r0 = blockIdx.y * 32;
  const int tx = threadIdx.x & 31, ty = threadIdx.x >> 5;
  for (int rr = ty; rr < 32; rr += 8)
    tile[rr][tx] = src[(size_t)(r0 + rr) * C + c0 + tx];
  __syncthreads();
  for (int rr = ty; rr < 32; rr += 8)
    dst[(size_t)(c0 + rr) * R + r0 + tx] = f2bf(tile[tx][rr]);
}

// Kernel 3b: plain fp32->bf16 cast (4 elems/thread)
__global__ __launch_bounds__(256) void cvt_bf16(
    const float* __restrict__ in, ushort_t* __restrict__ out)
{
  const int i = (blockIdx.x * 256 + threadIdx.x) * 4;
  float4 v = *(const float4*)(in + i);
  uint2 pk;
  pk.x = (unsigned)f2bf(v.x) | ((unsigned)f2bf(v.y) << 16);
  pk.y = (unsigned)f2bf(v.z) | ((unsigned)f2bf(v.w) << 16);
  *(uint2*)(out + i) = pk;
}

// ---------------------------------------------------------------------------
// Kernel 4: bf16 MFMA GEMM.  C[M,N] = A[M,K](bf16) @ Bt[N,K]^T + bias (+resid)
// out fp32 or bf16.  128x128 tile, BK=32, 4 waves, double-buffered LDS.
// ---------------------------------------------------------------------------
__global__ __launch_bounds__(256) void gemm_bf16(
    const ushort_t* __restrict__ A, const ushort_t* __restrict__ Bt,
    const float* __restrict__ bias, const float* __restrict__ resid,
    void* __restrict__ Cout, int M, int N, int K, int bf16_out)
{
  __shared__ ushort_t As[2][4096];
  __shared__ ushort_t Bs[2][4096];
  const int t = threadIdx.x;
  const int w = t >> 6, lane = t & 63;
  const int quad = lane >> 4, r = lane & 15;
  const int wm = w >> 1, wn = w & 1;
  const int bm = blockIdx.y * 128, bn = blockIdx.x * 128;
  f32x4 acc[4][4];
#pragma unroll
  for (int i = 0; i < 4; ++i)
#pragma unroll
    for (int j = 0; j < 4; ++j) acc[i][j] = (f32x4){0.f, 0.f, 0.f, 0.f};
  const ushort_t* Ab = A + (size_t)bm * K;
  const ushort_t* Bb = Bt + (size_t)bn * K;
  const int NIT = K >> 5;
  stage_tile(Ab, K, As[0]);
  stage_tile(Bb, K, Bs[0]);
  __syncthreads();
  for (int it = 0; it < NIT; ++it) {
    const int cur = it & 1;
    if (it + 1 < NIT) {
      stage_tile(Ab + (it + 1) * 32, K, As[cur ^ 1]);
      stage_tile(Bb + (it + 1) * 32, K, Bs[cur ^ 1]);
    }
    short8 af[4], bfg[4];
#pragma unroll
    for (int i = 0; i < 4; ++i)
      af[i] = *(const short8*)&As[cur][(wm * 64 + i * 16 + r) * 32 + quad * 8];
#pragma unroll
    for (int j = 0; j < 4; ++j)
      bfg[j] = *(const short8*)&Bs[cur][(wn * 64 + j * 16 + r) * 32 + quad * 8];
#pragma unroll
    for (int i = 0; i < 4; ++i)
#pragma unroll
      for (int j = 0; j < 4; ++j)
        acc[i][j] = MFMA16(af[i], bfg[j], acc[i][j]);
    __syncthreads();
  }
  if (bf16_out) {
    ushort_t* Cb = (ushort_t*)Cout;
#pragma unroll
    for (int j = 0; j < 4; ++j) {
      const int col = bn + wn * 64 + j * 16 + r;
      const float bia = bias[col];
#pragma unroll
      for (int i = 0; i < 4; ++i)
#pragma unroll
        for (int reg = 0; reg < 4; ++reg) {
          const int row = bm + wm * 64 + i * 16 + quad * 4 + reg;
          Cb[(size_t)row * N + col] = f2bf(acc[i][j][reg] + bia);
        }
    }
  } else {
    float* Cf = (float*)Cout;
#pragma unroll
    for (int j = 0; j < 4; ++j) {
      const int col = bn + wn * 64 + j * 16 + r;
      const float bia = bias[col];
#pragma unroll
      for (int i = 0; i < 4; ++i)
#pragma unroll
        for (int reg = 0; reg < 4; ++reg) {
          const int row = bm + wm * 64 + i * 16 + quad * 4 + reg;
          float v = acc[i][j][reg] + bia;
          if (resid) v += resid[(size_t)row * N + col];
          Cf[(size_t)row * N + col] = v;
        }
    }
  }
}

// ---------------------------------------------------------------------------
// Kernel 5: MFMA flash attention, bf16 Q/K/V in, bf16 out.
// grid (L/128, NH, B), 256 thr = 4 waves; wave w owns queries w*32..w*32+31.
// Per 64-key chunk:  S^T = K·Q^T (MFMA, A=K rows, B=Q rows in regs);
// softmax in C-layout (col=query) with 2 shfl_xor cross-quad reductions;
// P^T round-trips through per-wave LDS tile Pt[q][key] (write b64 from
// C-layout, read b128 as B-frag);  O^T += V^T·P^T with V staged transposed.
// All LDS strides = 72 bf16 (conflict-free for every access pattern here).
// ---------------------------------------------------------------------------
__global__ __launch_bounds__(256, 2) void fattn_mfma(
    const ushort_t* __restrict__ Q, const ushort_t* __restrict__ Kmat,
    const ushort_t* __restrict__ V, ushort_t* __restrict__ O, int Lk)
{
  __shared__ __align__(16) ushort_t Ks[64][72];      // [key][d]
  __shared__ __align__(16) ushort_t Vt[64][72];      // [d][key]
  __shared__ __align__(16) ushort_t Pt[4][32][72];   // per-wave [q_local][key]
  const int t = threadIdx.x;
  const int w = t >> 6, lane = t & 63;
  const int quad = lane >> 4, r = lane & 15;
  const int h = blockIdx.y, b = blockIdx.z;
  const int q0 = blockIdx.x * 128;
  const size_t hoff = (size_t)h * 64;
  const ushort_t* Qb = Q + ((size_t)b * 1024 + q0) * 512 + hoff;
  const ushort_t* Kb = Kmat + (size_t)b * Lk * 512 + hoff;
  const ushort_t* Vb = V + (size_t)b * Lk * 512 + hoff;

  // Q B-fragments, resident in regs for the whole kernel: qb[ct][ki]
  short8 qb[2][2];
#pragma unroll
  for (int ct = 0; ct < 2; ++ct)
#pragma unroll
    for (int ki = 0; ki < 2; ++ki)
      qb[ct][ki] = *(const short8*)(Qb + (size_t)(w * 32 + ct * 16 + r) * 512 +
                                    ki * 32 + quad * 8);

  f32x4 oacc[4][2];
#pragma unroll
  for (int rt = 0; rt < 4; ++rt)
#pragma unroll
    for (int ct = 0; ct < 2; ++ct) oacc[rt][ct] = (f32x4){0.f, 0.f, 0.f, 0.f};
  float m_[2] = {-1e30f, -1e30f};
  float l_[2] = {0.f, 0.f};

  // K/V chunk staging: thread (w,lane) loads key row `lane`, d-cols (w+4j)*8.
  uint4 kr[2], vr[2], kn[2], vn[2];
  auto ldkv = [&](int k0, uint4* kp, uint4* vp) {
#pragma unroll
    for (int j = 0; j < 2; ++j) {
      const int dof = (w + 4 * j) * 8;
      kp[j] = *(const uint4*)(Kb + (size_t)(k0 + lane) * 512 + dof);
      vp[j] = *(const uint4*)(Vb + (size_t)(k0 + lane) * 512 + dof);
    }
  };
  auto stkv = [&](const uint4* kp, const uint4* vp) {
#pragma unroll
    for (int j = 0; j < 2; ++j) {
      const int dof = (w + 4 * j) * 8;
      *(uint4*)&Ks[lane][dof] = kp[j];
      const ushort_t* vv = (const ushort_t*)&vp[j];
#pragma unroll
      for (int i = 0; i < 8; ++i) Vt[dof + i][lane] = vv[i];  // transpose
    }
  };

  ldkv(0, kr, vr);
  const int nch = Lk >> 6;
  for (int c = 0; c < nch; ++c) {
    stkv(kr, vr);
    __syncthreads();
    if (c + 1 < nch) ldkv((c + 1) << 6, kn, vn);  // in flight over compute

    // ---- S^T = K · Q^T   (rows=keys, cols=queries) ----
    f32x4 sacc[4][2];
#pragma unroll
    for (int rt = 0; rt < 4; ++rt)
#pragma unroll
      for (int ct = 0; ct < 2; ++ct) sacc[rt][ct] = (f32x4){0.f, 0.f, 0.f, 0.f};
#pragma unroll
    for (int ki = 0; ki < 2; ++ki) {
      short8 kf[4];
#pragma unroll
      for (int rt = 0; rt < 4; ++rt)
        kf[rt] = *(const short8*)&Ks[rt * 16 + r][ki * 32 + quad * 8];
#pragma unroll
      for (int rt = 0; rt < 4; ++rt)
#pragma unroll
        for (int ct = 0; ct < 2; ++ct)
          sacc[rt][ct] = MFMA16(kf[rt], qb[ct][ki], sacc[rt][ct]);
    }

    // ---- online softmax per ct (lane's col = query lane&15 + 16ct) ----
#pragma unroll
    for (int ct = 0; ct < 2; ++ct) {
      float vmax = sacc[0][ct][0];
#pragma unroll
      for (int rt = 0; rt < 4; ++rt)
#pragma unroll
        for (int reg = 0; reg < 4; ++reg) vmax = fmaxf(vmax, sacc[rt][ct][reg]);
      vmax = fmaxf(vmax, __shfl_xor(vmax, 16, 64));
      vmax = fmaxf(vmax, __shfl_xor(vmax, 32, 64));
      const float mnew = fmaxf(m_[ct], vmax * 0.125f);
      const float corr = __expf(m_[ct] - mnew);
      m_[ct] = mnew;
      float ps = 0.f;
#pragma unroll
      for (int rt = 0; rt < 4; ++rt) {
        float p0 = __expf(fmaf(sacc[rt][ct][0], 0.125f, -mnew));
        float p1 = __expf(fmaf(sacc[rt][ct][1], 0.125f, -mnew));
        float p2 = __expf(fmaf(sacc[rt][ct][2], 0.125f, -mnew));
        float p3 = __expf(fmaf(sacc[rt][ct][3], 0.125f, -mnew));
        ps += (p0 + p1) + (p2 + p3);
        uint2 pk;
        pk.x = (unsigned)f2bf(p0) | ((unsigned)f2bf(p1) << 16);
        pk.y = (unsigned)f2bf(p2) | ((unsigned)f2bf(p3) << 16);
        // P^T stored as Pt[q_local][key]; keys rt*16 + quad*4 .. +3
        *(uint2*)&Pt[w][ct * 16 + r][rt * 16 + quad * 4] = pk;
      }
      ps += __shfl_xor(ps, 16, 64);
      ps += __shfl_xor(ps, 32, 64);
      l_[ct] = l_[ct] * corr + ps;
#pragma unroll
      for (int rt = 0; rt < 4; ++rt)
#pragma unroll
        for (int reg = 0; reg < 4; ++reg) oacc[rt][ct][reg] *= corr;
    }

    // ---- O^T += V^T · P^T  (rows=d, cols=queries, k=keys) ----
#pragma unroll
    for (int ki = 0; ki < 2; ++ki) {
      short8 vf[4], pf[2];
#pragma unroll
      for (int rt = 0; rt < 4; ++rt)
        vf[rt] = *(const short8*)&Vt[rt * 16 + r][ki * 32 + quad * 8];
#pragma unroll
      for (int ct = 0; ct < 2; ++ct)
        pf[ct] = *(const short8*)&Pt[w][ct * 16 + r][ki * 32 + quad * 8];
#pragma unroll
      for (int rt = 0; rt < 4; ++rt)
#pragma unroll
        for (int ct = 0; ct < 2; ++ct)
          oacc[rt][ct] = MFMA16(vf[rt], pf[ct], oacc[rt][ct]);
    }
    __syncthreads();
#pragma unroll
    for (int j = 0; j < 2; ++j) { kr[j] = kn[j]; vr[j] = vn[j]; }
  }

  // ---- epilogue: O[q][d] = O^T[d][q] / l ----
#pragma unroll
  for (int ct = 0; ct < 2; ++ct) {
    const float inv = 1.0f / l_[ct];
    const int qg = q0 + w * 32 + ct * 16 + r;
    ushort_t* op = O + ((size_t)b * 1024 + qg) * 512 + hoff;
#pragma unroll
    for (int rt = 0; rt < 4; ++rt) {
      uint2 pk;
      pk.x = (unsigned)f2bf(oacc[rt][ct][0] * inv) |
             ((unsigned)f2bf(oacc[rt][ct][1] * inv) << 16);
      pk.y = (unsigned)f2bf(oacc[rt][ct][2] * inv) |
             ((unsigned)f2bf(oacc[rt][ct][3] * inv) << 16);
      *(uint2*)(op + rt * 16 + quad * 4) = pk;
    }
  }
}

// ---------------------------------------------------------------------------
// Kernel 6: MoE fc_in for ONE expert slot ks.  grid (16, 8, B), 256 thr.
// ---------------------------------------------------------------------------
__global__ __launch_bounds__(256) void moe_fcin(
    const ushort_t* __restrict__ Xm, const ushort_t* __restrict__ WiT,
    const float* __restrict__ Bi, const float* __restrict__ tw,
    const int* __restrict__ ti, ushort_t* __restrict__ Hid, int ks)
{
  __shared__ ushort_t As[2][4096];
  __shared__ ushort_t Bv[2][4096];
  __shared__ ushort_t Bg[2][4096];
  const int t = threadIdx.x;
  const int w = t >> 6, lane = t & 63;
  const int quad = lane >> 4, r = lane & 15;
  const int wm = w >> 1, wn = w & 1;
  const int b = blockIdx.z;
  const int e = ti[b * 2 + ks];
  const float wq = tw[b * 2 + ks];
  const int r0 = blockIdx.y * 128, n0 = blockIdx.x * 128;
  const ushort_t* Ab = Xm + ((size_t)b * 1024 + r0) * 512;
  const ushort_t* Wv = WiT + (size_t)e * 4096 * 512 + (size_t)n0 * 512;
  const ushort_t* Wg = Wv + (size_t)2048 * 512;
  f32x4 av[4][4], ag[4][4];
#pragma unroll
  for (int i = 0; i < 4; ++i)
#pragma unroll
    for (int j = 0; j < 4; ++j) {
      av[i][j] = (f32x4){0.f, 0.f, 0.f, 0.f};
      ag[i][j] = (f32x4){0.f, 0.f, 0.f, 0.f};
    }
  stage_tile(Ab, 512, As[0]);
  stage_tile(Wv, 512, Bv[0]);
  stage_tile(Wg, 512, Bg[0]);
  __syncthreads();
  for (int it = 0; it < 16; ++it) {
    const int cur = it & 1;
    if (it + 1 < 16) {
      stage_tile(Ab + (it + 1) * 32, 512, As[cur ^ 1]);
      stage_tile(Wv + (it + 1) * 32, 512, Bv[cur ^ 1]);
      stage_tile(Wg + (it + 1) * 32, 512, Bg[cur ^ 1]);
    }
    short8 af[4], bv[4], bg[4];
#pragma unroll
    for (int i = 0; i < 4; ++i)
      af[i] = *(const short8*)&As[cur][(wm * 64 + i * 16 + r) * 32 + quad * 8];
#pragma unroll
    for (int j = 0; j < 4; ++j) {
      bv[j] = *(const short8*)&Bv[cur][(wn * 64 + j * 16 + r) * 32 + quad * 8];
      bg[j] = *(const short8*)&Bg[cur][(wn * 64 + j * 16 + r) * 32 + quad * 8];
    }
#pragma unroll
    for (int i = 0; i < 4; ++i)
#pragma unroll
      for (int j = 0; j < 4; ++j) {
        av[i][j] = MFMA16(af[i], bv[j], av[i][j]);
        ag[i][j] = MFMA16(af[i], bg[j], ag[i][j]);
      }
    __syncthreads();
  }
  ushort_t* Hb = Hid + (size_t)b * 1024 * 2048;
#pragma unroll
  for (int j = 0; j < 4; ++j) {
    const int col = n0 + wn * 64 + j * 16 + r;
    const float bval = Bi[(size_t)e * 4096 + col];
    const float bgat = Bi[(size_t)e * 4096 + 2048 + col];
#pragma unroll
    for (int i = 0; i < 4; ++i)
#pragma unroll
      for (int reg = 0; reg < 4; ++reg) {
        const int lrow = r0 + wm * 64 + i * 16 + quad * 4 + reg;
        float vv = av[i][j][reg] + bval;
        float gg = ag[i][j][reg] + bgat;
        float hv = vv * (gg / (1.0f + __expf(-gg))) * wq;
        Hb[(size_t)lrow * 2048 + col] = f2bf(hv);
      }
  }
}

// ---------------------------------------------------------------------------
// Kernel 7: MoE fc_out for ONE slot.  grid (4, 8, B), 256 thr.
// first=1: Out = X2 + acc + (tw0*bo_e0 + tw1*bo_e1);  first=0: Out += acc
// ---------------------------------------------------------------------------
__global__ __launch_bounds__(256) void moe_fcout(
    const ushort_t* __restrict__ Hid, const ushort_t* __restrict__ WoT,
    const float* __restrict__ Bo, const float* __restrict__ X2,
    const float* __restrict__ tw, const int* __restrict__ ti,
    float* __restrict__ Out, int ks, int first)
{
  __shared__ ushort_t As[2][4096];
  __shared__ ushort_t Bs[2][4096];
  const int t = threadIdx.x;
  const int w = t >> 6, lane = t & 63;
  const int quad = lane >> 4, r = lane & 15;
  const int wm = w >> 1, wn = w & 1;
  const int b = blockIdx.z;
  const int e = ti[b * 2 + ks];
  const int r0 = blockIdx.y * 128, n0 = blockIdx.x * 128;
  f32x4 acc[4][4];
#pragma unroll
  for (int i = 0; i < 4; ++i)
#pragma unroll
    for (int j = 0; j < 4; ++j) acc[i][j] = (f32x4){0.f, 0.f, 0.f, 0.f};
  const ushort_t* Ab = Hid + ((size_t)b * 1024 + r0) * 2048;
  const ushort_t* Bb = WoT + (size_t)e * 512 * 2048 + (size_t)n0 * 2048;
  stage_tile(Ab, 2048, As[0]);
  stage_tile(Bb, 2048, Bs[0]);
  __syncthreads();
  for (int it = 0; it < 64; ++it) {
    const int cur = it & 1;
    if (it + 1 < 64) {
      stage_tile(Ab + (it + 1) * 32, 2048, As[cur ^ 1]);
      stage_tile(Bb + (it + 1) * 32, 2048, Bs[cur ^ 1]);
    }
    short8 af[4], bfg[4];
#pragma unroll
    for (int i = 0; i < 4; ++i)
      af[i] = *(const short8*)&As[cur][(wm * 64 + i * 16 + r) * 32 + quad * 8];
#pragma unroll
    for (int j = 0; j < 4; ++j)
      bfg[j] = *(const short8*)&Bs[cur][(wn * 64 + j * 16 + r) * 32 + quad * 8];
#pragma unroll
    for (int i = 0; i < 4; ++i)
#pragma unroll
      for (int j = 0; j < 4; ++j)
        acc[i][j] = MFMA16(af[i], bfg[j], acc[i][j]);
    __syncthreads();
  }
  const int e0 = ti[b * 2], e1 = ti[b * 2 + 1];
  const float tw0 = tw[b * 2], tw1 = tw[b * 2 + 1];
#pragma unroll
  for (int j = 0; j < 4; ++j) {
    const int col = n0 + wn * 64 + j * 16 + r;
    const float badd = first ? (tw0 * Bo[(size_t)e0 * 512 + col] +
                                tw1 * Bo[(size_t)e1 * 512 + col]) : 0.f;
#pragma unroll
    for (int i = 0; i < 4; ++i)
#pragma unroll
      for (int reg = 0; reg < 4; ++reg) {
        const size_t row = (size_t)b * 1024 + r0 + wm * 64 + i * 16 + quad * 4 + reg;
        const size_t idx = row * 512 + col;
        const float base = first ? X2[idx] : Out[idx];
        Out[idx] = base + acc[i][j][reg] + badd;
      }
  }
}

// ---------------------------------------------------------------------------
// Launch.  Workspace: 93 MiB total.
// ---------------------------------------------------------------------------
extern "C" void kernel_launch(void* const* d_in, const int* in_sizes, int n_in,
                              void* d_out, int out_size, void* d_ws, size_t ws_size,
                              hipStream_t stream) {
  const float* x        = (const float*)d_in[0];
  const float* scene    = (const float*)d_in[1];
  const float* t_in     = (const float*)d_in[2];
  const float* sn_g     = (const float*)d_in[3];
  const float* sn_b     = (const float*)d_in[4];
  const float* ca_wq    = (const float*)d_in[5];
  const float* ca_bq    = (const float*)d_in[6];
  const float* ca_wk    = (const float*)d_in[7];
  const float* ca_bk    = (const float*)d_in[8];
  const float* ca_wv    = (const float*)d_in[9];
  const float* ca_bv    = (const float*)d_in[10];
  const float* ca_wo    = (const float*)d_in[11];
  const float* ca_bo    = (const float*)d_in[12];
  const float* sa_wq    = (const float*)d_in[13];
  const float* sa_bq    = (const float*)d_in[14];
  const float* sa_wk    = (const float*)d_in[15];
  const float* sa_bk    = (const float*)d_in[16];
  const float* sa_wv    = (const float*)d_in[17];
  const float* sa_bv    = (const float*)d_in[18];
  const float* sa_wo    = (const float*)d_in[19];
  const float* sa_bo    = (const float*)d_in[20];
  const float* ne_w1    = (const float*)d_in[21];
  const float* ne_b1    = (const float*)d_in[22];
  const float* ne_w2    = (const float*)d_in[23];
  const float* ne_b2    = (const float*)d_in[24];
  const float* ncsa_w   = (const float*)d_in[25];
  const float* ncsa_b   = (const float*)d_in[26];
  const float* moe_w    = (const float*)d_in[27];
  const float* moe_b    = (const float*)d_in[28];
  const float* router_w = (const float*)d_in[29];
  const float* fc_in_w  = (const float*)d_in[30];
  const float* fc_in_b  = (const float*)d_in[31];
  const float* fc_out_w = (const float*)d_in[32];
  const float* fc_out_b = (const float*)d_in[33];
  float* out = (float*)d_out;

  // ---- workspace layout (MiB offsets; 93 MiB total) ----
  char* W = (char*)d_ws;
  const size_t MB = 1u << 20;
  float* ncsa_mod = (float*)W;
  float* moe_mod  = ncsa_mod + 8192;
  float* tw       = moe_mod + 8192;
  int*   ti       = (int*)(tw + 16);
  ushort_t* wT      = (ushort_t*)(W + 1 * MB);
  ushort_t* fciT    = (ushort_t*)(W + 5 * MB);
  ushort_t* fcoT    = (ushort_t*)(W + 37 * MB);
  ushort_t* xin_bf  = (ushort_t*)(W + 53 * MB);
  ushort_t* attn_bf = xin_bf;
  ushort_t* scene_bf= (ushort_t*)(W + 61 * MB);
  ushort_t* qf = (ushort_t*)(W + 65 * MB);
  ushort_t* kf = (ushort_t*)(W + 73 * MB);
  ushort_t* vf = (ushort_t*)(W + 81 * MB);
  ushort_t* hid = (ushort_t*)(W + 61 * MB);
  float* x1 = out;

  const int WSZ = 512 * 512;

  noise_kernel<<<dim3(B_), dim3(256), 0, stream>>>(
      t_in, ne_w1, ne_b1, ne_w2, ne_b2, ncsa_w, ncsa_b, moe_w, moe_b, router_w,
      ncsa_mod, moe_mod, tw, ti);

  // weight prep
  transpose_cvt<<<dim3(16, 16, 1), 256, 0, stream>>>(ca_wq, wT + 0 * WSZ, 512, 512, 0, 0);
  transpose_cvt<<<dim3(16, 16, 1), 256, 0, stream>>>(ca_wk, wT + 1 * WSZ, 512, 512, 0, 0);
  transpose_cvt<<<dim3(16, 16, 1), 256, 0, stream>>>(ca_wv, wT + 2 * WSZ, 512, 512, 0, 0);
  transpose_cvt<<<dim3(16, 16, 1), 256, 0, stream>>>(ca_wo, wT + 3 * WSZ, 512, 512, 0, 0);
  transpose_cvt<<<dim3(16, 16, 1), 256, 0, stream>>>(sa_wq, wT + 4 * WSZ, 512, 512, 0, 0);
  transpose_cvt<<<dim3(16, 16, 1), 256, 0, stream>>>(sa_wk, wT + 5 * WSZ, 512, 512, 0, 0);
  transpose_cvt<<<dim3(16, 16, 1), 256, 0, stream>>>(sa_wv, wT + 6 * WSZ, 512, 512, 0, 0);
  transpose_cvt<<<dim3(16, 16, 1), 256, 0, stream>>>(sa_wo, wT + 7 * WSZ, 512, 512, 0, 0);
  transpose_cvt<<<dim3(128, 16, 8), 256, 0, stream>>>(fc_in_w, fciT, 512, 4096,
                                                      (long)512 * 4096, (long)512 * 4096);
  transpose_cvt<<<dim3(16, 64, 8), 256, 0, stream>>>(fc_out_w, fcoT, 2048, 512,
                                                     (long)2048 * 512, (long)2048 * 512);
  cvt_bf16<<<dim3(2048), 256, 0, stream>>>(scene, scene_bf);

  // scene cross-attention
  ln_mod_kernel<<<dim3(8192), 256, 0, stream>>>(x, sn_g, sn_b, nullptr, xin_bf);
  gemm_bf16<<<dim3(4, 64), 256, 0, stream>>>(xin_bf, wT + 0 * WSZ, ca_bq, nullptr, qf, 8192, 512, 512, 1);
  gemm_bf16<<<dim3(4, 32), 256, 0, stream>>>(scene_bf, wT + 1 * WSZ, ca_bk, nullptr, kf, 4096, 512, 512, 1);
  gemm_bf16<<<dim3(4, 32), 256, 0, stream>>>(scene_bf, wT + 2 * WSZ, ca_bv, nullptr, vf, 4096, 512, 512, 1);
  fattn_mfma<<<dim3(8, NH_, B_), 256, 0, stream>>>(qf, kf, vf, attn_bf, NS_);
  gemm_bf16<<<dim3(4, 64), 256, 0, stream>>>(attn_bf, wT + 3 * WSZ, ca_bo, x, x1, 8192, 512, 512, 0);

  // noise-conditioned self-attention (AdaLN)
  ln_mod_kernel<<<dim3(8192), 256, 0, stream>>>(x1, nullptr, nullptr, ncsa_mod, xin_bf);
  gemm_bf16<<<dim3(4, 64), 256, 0, stream>>>(xin_bf, wT + 4 * WSZ, sa_bq, nullptr, qf, 8192, 512, 512, 1);
  gemm_bf16<<<dim3(4, 64), 256, 0, stream>>>(xin_bf, wT + 5 * WSZ, sa_bk, nullptr, kf, 8192, 512, 512, 1);
  gemm_bf16<<<dim3(4, 64), 256, 0, stream>>>(xin_bf, wT + 6 * WSZ, sa_bv, nullptr, vf, 8192, 512, 512, 1);
  fattn_mfma<<<dim3(8, NH_, B_), 256, 0, stream>>>(qf, kf, vf, attn_bf, L_);
  gemm_bf16<<<dim3(4, 64), 256, 0, stream>>>(attn_bf, wT + 7 * WSZ, sa_bo, out, out, 8192, 512, 512, 0);

  // MoE: AdaLN -> per-slot fc_in/fc_out, accumulating into d_out
  ln_mod_kernel<<<dim3(8192), 256, 0, stream>>>(out, nullptr, nullptr, moe_mod, xin_bf);
  moe_fcin<<<dim3(16, 8, B_), 256, 0, stream>>>(xin_bf, fciT, fc_in_b, tw, ti, hid, 0);
  moe_fcout<<<dim3(4, 8, B_), 256, 0, stream>>>(hid, fcoT, fc_out_b, out, tw, ti, out, 0, 1);
  moe_fcin<<<dim3(16, 8, B_), 256, 0, stream>>>(xin_bf, fciT, fc_in_b, tw, ti, hid, 1);
  moe_fcout<<<dim3(4, 8, B_), 256, 0, stream>>>(hid, fcoT, fc_out_b, out, tw, ti, out, 1, 0);
}

// Round 7
// 829.155 us; speedup vs baseline: 16.9659x; 1.0756x over previous
//
#include <hip/hip_runtime.h>
#include <math.h>

typedef unsigned short ushort_t;
typedef __attribute__((ext_vector_type(8))) short short8;
typedef __attribute__((ext_vector_type(4))) float f32x4;

#define B_   8
#define L_   1024
#define NS_  512
#define D_   512
#define NH_  8
#define HE_  2048
#define EPS_ 1e-5f

#define MFMA16(a, b, c) __builtin_amdgcn_mfma_f32_16x16x32_bf16(a, b, c, 0, 0, 0)
#define GL2LDS(g, l) __builtin_amdgcn_global_load_lds( \
    (const __attribute__((address_space(1))) unsigned int*)(g), \
    (__attribute__((address_space(3))) unsigned int*)(l), 16, 0, 0)

__device__ __forceinline__ ushort_t f2bf(float f) {
  unsigned u = __float_as_uint(f);
  unsigned r = (u + 0x7fffu + ((u >> 16) & 1u)) >> 16;
  return (ushort_t)r;
}

// ---------------------------------------------------------------------------
// Stage a 128x32 bf16 tile (8 KB) from global (row stride ld bf16) into LDS
// via async global_load_lds width=16.  512 chunks; thread t stages 2.
// ---------------------------------------------------------------------------
__device__ __forceinline__ void stage_tile(const ushort_t* __restrict__ g0,
                                           int ld, ushort_t* lds) {
  const int t = threadIdx.x;
  const int w = t >> 6, lane = t & 63;
#pragma unroll
  for (int j = 0; j < 2; ++j) {
    const int c = w * 64 + j * 256 + lane;
    const int row = c >> 2, col = (c & 3) * 8;
    GL2LDS(g0 + (size_t)row * ld + col, lds + (size_t)(w * 64 + j * 256) * 8);
  }
}

// ---------------------------------------------------------------------------
// Kernel 1a: noise embedding MLP + router top-2.  grid (B), 256 thr.
// Writes nc[b][256] for mod_proj, plus tw/ti.
// ---------------------------------------------------------------------------
__global__ __launch_bounds__(256) void noise_embed(
    const float* __restrict__ t_in,
    const float* __restrict__ w1, const float* __restrict__ b1,
    const float* __restrict__ w2, const float* __restrict__ b2,
    const float* __restrict__ rw,
    float* __restrict__ nc_out,
    float* __restrict__ tw_out, int* __restrict__ ti_out)
{
  const int b = blockIdx.x;
  const int t = threadIdx.x;
  __shared__ float temb[512];
  __shared__ float h1[256];
  __shared__ float ncs[256];
  const float tv = t_in[b];
  {
    float fr = __expf(-logf(10000.0f) * (float)t / 255.0f);
    float ang = tv * fr;
    temb[t] = cosf(ang);
    temb[256 + t] = sinf(ang);
  }
  __syncthreads();
  {
    float s = b1[t];
#pragma unroll 8
    for (int i = 0; i < 512; ++i) s += temb[i] * w1[i * 256 + t];
    h1[t] = s / (1.0f + __expf(-s));
  }
  __syncthreads();
  {
    float s = b2[t];
#pragma unroll 8
    for (int i = 0; i < 256; ++i) s += h1[i] * w2[i * 256 + t];
    ncs[t] = s;
    nc_out[b * 256 + t] = s;
  }
  __syncthreads();
  if (t == 0) {
    float lg[8];
    for (int e = 0; e < 8; ++e) {
      float s = 0.f;
      for (int i = 0; i < 256; ++i) s += ncs[i] * rw[i * 8 + e];
      lg[e] = s;
    }
    float mx = lg[0];
    for (int e = 1; e < 8; ++e) mx = fmaxf(mx, lg[e]);
    float z = 0.f, p[8];
    for (int e = 0; e < 8; ++e) { p[e] = __expf(lg[e] - mx); z += p[e]; }
    for (int e = 0; e < 8; ++e) p[e] /= z;
    int i0 = 0;
    for (int e = 1; e < 8; ++e) if (p[e] > p[i0]) i0 = e;
    int i1 = (i0 == 0) ? 1 : 0;
    for (int e = 0; e < 8; ++e) if (e != i0 && p[e] > p[i1]) i1 = e;
    float s01 = fmaxf(p[i0] + p[i1], 1e-8f);
    tw_out[b * 2 + 0] = p[i0] / s01;
    tw_out[b * 2 + 1] = p[i1] / s01;
    ti_out[b * 2 + 0] = i0;
    ti_out[b * 2 + 1] = i1;
  }
}

// ---------------------------------------------------------------------------
// Kernel 1b: AdaLN modulation projections.  grid (B, 8), 256 thr.
// Block (b,cg): 128 cols of both mods.  threads 0-127 -> ncsa, 128-255 -> moe.
// ---------------------------------------------------------------------------
__global__ __launch_bounds__(256) void mod_proj(
    const float* __restrict__ nc,
    const float* __restrict__ ncsa_w, const float* __restrict__ ncsa_b,
    const float* __restrict__ moe_w, const float* __restrict__ moe_b,
    float* __restrict__ ncsa_mod, float* __restrict__ moe_mod)
{
  const int b = blockIdx.x, cg = blockIdx.y;
  const int t = threadIdx.x;
  __shared__ float ncs[256];
  ncs[t] = nc[b * 256 + t];
  __syncthreads();
  const int col = cg * 128 + (t & 127);
  const int half = t >> 7;
  const float* wsel = half ? moe_w : ncsa_w;
  const float* bsel = half ? moe_b : ncsa_b;
  float* osel = half ? moe_mod : ncsa_mod;
  float s = bsel[col];
#pragma unroll 8
  for (int i = 0; i < 256; ++i) s += ncs[i] * wsel[(size_t)i * 1024 + col];
  osel[b * 1024 + col] = s;
}

// ---------------------------------------------------------------------------
// Kernel 2: LayerNorm + modulation -> bf16 output.
// ---------------------------------------------------------------------------
__global__ __launch_bounds__(256) void ln_mod_kernel(
    const float* __restrict__ X, const float* __restrict__ gvec,
    const float* __restrict__ bvec, const float* __restrict__ mod,
    ushort_t* __restrict__ Y)
{
  const int row = blockIdx.x;
  const int b = row >> 10;
  const int t = threadIdx.x;
  const float* xr = X + (size_t)row * 512;
  float2 v = *(const float2*)(xr + t * 2);
  float s = v.x + v.y;
  float q = v.x * v.x + v.y * v.y;
#pragma unroll
  for (int off = 32; off > 0; off >>= 1) {
    s += __shfl_down(s, off, 64);
    q += __shfl_down(q, off, 64);
  }
  __shared__ float ws_[4], wq_[4], smu[1], sinv[1];
  if ((t & 63) == 0) { ws_[t >> 6] = s; wq_[t >> 6] = q; }
  __syncthreads();
  if (t == 0) {
    float S = ws_[0] + ws_[1] + ws_[2] + ws_[3];
    float Q = wq_[0] + wq_[1] + wq_[2] + wq_[3];
    float mu = S * (1.0f / 512.0f);
    float var = Q * (1.0f / 512.0f) - mu * mu;
    smu[0] = mu;
    sinv[0] = rsqrtf(var + EPS_);
  }
  __syncthreads();
  const float mu = smu[0], inv = sinv[0];
  const int d0 = t * 2;
  float scx, scy, shx, shy;
  if (mod) {
    const float* mrow = mod + (size_t)b * 1024;
    scx = 1.0f + mrow[512 + d0]; scy = 1.0f + mrow[512 + d0 + 1];
    shx = mrow[d0];              shy = mrow[d0 + 1];
  } else {
    scx = gvec[d0]; scy = gvec[d0 + 1];
    shx = bvec[d0]; shy = bvec[d0 + 1];
  }
  float ox = (v.x - mu) * inv * scx + shx;
  float oy = (v.y - mu) * inv * scy + shy;
  unsigned pk = (unsigned)f2bf(ox) | ((unsigned)f2bf(oy) << 16);
  *(unsigned*)(Y + (size_t)row * 512 + d0) = pk;
}

// ---------------------------------------------------------------------------
// Kernel 3a: tiled transpose + fp32->bf16:  in[z][R][C] -> out[z][C][R]
// ---------------------------------------------------------------------------
__global__ __launch_bounds__(256) void transpose_cvt(
    const float* __restrict__ in, ushort_t* __restrict__ out,
    int R, int C, long ibs, long obs)
{
  __shared__ float tile[32][33];
  const float* src = in + (size_t)blockIdx.z * ibs;
  ushort_t* dst = out + (size_t)blockIdx.z * obs;
  const int c0 = blockIdx.x * 32, r0 = blockIdx.y * 32;
  const int tx = threadIdx.x & 31, ty = threadIdx.x >> 5;
  for (int rr = ty; rr < 32; rr += 8)
    tile[rr][tx] = src[(size_t)(r0 + rr) * C + c0 + tx];
  __syncthreads();
  for (int rr = ty; rr < 32; rr += 8)
    dst[(size_t)(c0 + rr) * R + r0 + tx] = f2bf(tile[tx][rr]);
}

// Kernel 3a': 8 dense 512x512 transposes in one dispatch (z selects source).
struct P8 { const float* p[8]; };
__global__ __launch_bounds__(256) void transpose_cvt8(
    P8 srcs, ushort_t* __restrict__ out)
{
  __shared__ float tile[32][33];
  const float* src = srcs.p[blockIdx.z];
  ushort_t* dst = out + (size_t)blockIdx.z * 512 * 512;
  const int c0 = blockIdx.x * 32, r0 = blockIdx.y * 32;
  const int tx = threadIdx.x & 31, ty = threadIdx.x >> 5;
  for (int rr = ty; rr < 32; rr += 8)
    tile[rr][tx] = src[(size_t)(r0 + rr) * 512 + c0 + tx];
  __syncthreads();
  for (int rr = ty; rr < 32; rr += 8)
    dst[(size_t)(c0 + rr) * 512 + r0 + tx] = f2bf(tile[tx][rr]);
}

// Kernel 3b: plain fp32->bf16 cast (4 elems/thread)
__global__ __launch_bounds__(256) void cvt_bf16(
    const float* __restrict__ in, ushort_t* __restrict__ out)
{
  const int i = (blockIdx.x * 256 + threadIdx.x) * 4;
  float4 v = *(const float4*)(in + i);
  uint2 pk;
  pk.x = (unsigned)f2bf(v.x) | ((unsigned)f2bf(v.y) << 16);
  pk.y = (unsigned)f2bf(v.z) | ((unsigned)f2bf(v.w) << 16);
  *(uint2*)(out + i) = pk;
}

// ---------------------------------------------------------------------------
// Kernel 4: bf16 MFMA GEMM.  C[M,N] = A[M,K](bf16) @ Bt[N,K]^T + bias (+resid)
// out fp32 or bf16.  128x128 tile, BK=32, 4 waves, double-buffered LDS.
// ---------------------------------------------------------------------------
__global__ __launch_bounds__(256) void gemm_bf16(
    const ushort_t* __restrict__ A, const ushort_t* __restrict__ Bt,
    const float* __restrict__ bias, const float* __restrict__ resid,
    void* __restrict__ Cout, int M, int N, int K, int bf16_out)
{
  __shared__ ushort_t As[2][4096];
  __shared__ ushort_t Bs[2][4096];
  const int t = threadIdx.x;
  const int w = t >> 6, lane = t & 63;
  const int quad = lane >> 4, r = lane & 15;
  const int wm = w >> 1, wn = w & 1;
  const int bm = blockIdx.y * 128, bn = blockIdx.x * 128;
  f32x4 acc[4][4];
#pragma unroll
  for (int i = 0; i < 4; ++i)
#pragma unroll
    for (int j = 0; j < 4; ++j) acc[i][j] = (f32x4){0.f, 0.f, 0.f, 0.f};
  const ushort_t* Ab = A + (size_t)bm * K;
  const ushort_t* Bb = Bt + (size_t)bn * K;
  const int NIT = K >> 5;
  stage_tile(Ab, K, As[0]);
  stage_tile(Bb, K, Bs[0]);
  __syncthreads();
  for (int it = 0; it < NIT; ++it) {
    const int cur = it & 1;
    if (it + 1 < NIT) {
      stage_tile(Ab + (it + 1) * 32, K, As[cur ^ 1]);
      stage_tile(Bb + (it + 1) * 32, K, Bs[cur ^ 1]);
    }
    short8 af[4], bfg[4];
#pragma unroll
    for (int i = 0; i < 4; ++i)
      af[i] = *(const short8*)&As[cur][(wm * 64 + i * 16 + r) * 32 + quad * 8];
#pragma unroll
    for (int j = 0; j < 4; ++j)
      bfg[j] = *(const short8*)&Bs[cur][(wn * 64 + j * 16 + r) * 32 + quad * 8];
#pragma unroll
    for (int i = 0; i < 4; ++i)
#pragma unroll
      for (int j = 0; j < 4; ++j)
        acc[i][j] = MFMA16(af[i], bfg[j], acc[i][j]);
    __syncthreads();
  }
  if (bf16_out) {
    ushort_t* Cb = (ushort_t*)Cout;
#pragma unroll
    for (int j = 0; j < 4; ++j) {
      const int col = bn + wn * 64 + j * 16 + r;
      const float bia = bias[col];
#pragma unroll
      for (int i = 0; i < 4; ++i)
#pragma unroll
        for (int reg = 0; reg < 4; ++reg) {
          const int row = bm + wm * 64 + i * 16 + quad * 4 + reg;
          Cb[(size_t)row * N + col] = f2bf(acc[i][j][reg] + bia);
        }
    }
  } else {
    float* Cf = (float*)Cout;
#pragma unroll
    for (int j = 0; j < 4; ++j) {
      const int col = bn + wn * 64 + j * 16 + r;
      const float bia = bias[col];
#pragma unroll
      for (int i = 0; i < 4; ++i)
#pragma unroll
        for (int reg = 0; reg < 4; ++reg) {
          const int row = bm + wm * 64 + i * 16 + quad * 4 + reg;
          float v = acc[i][j][reg] + bia;
          if (resid) v += resid[(size_t)row * N + col];
          Cf[(size_t)row * N + col] = v;
        }
    }
  }
}

// ---------------------------------------------------------------------------
// Kernel 5: MFMA flash attention, bf16 Q/K/V in, bf16 out.
// grid (L/128, NH, B), 256 thr = 4 waves; wave w owns queries w*32..w*32+31.
// ---------------------------------------------------------------------------
__global__ __launch_bounds__(256, 2) void fattn_mfma(
    const ushort_t* __restrict__ Q, const ushort_t* __restrict__ Kmat,
    const ushort_t* __restrict__ V, ushort_t* __restrict__ O, int Lk)
{
  __shared__ __align__(16) ushort_t Ks[64][72];      // [key][d]
  __shared__ __align__(16) ushort_t Vt[64][72];      // [d][key]
  __shared__ __align__(16) ushort_t Pt[4][32][72];   // per-wave [q_local][key]
  const int t = threadIdx.x;
  const int w = t >> 6, lane = t & 63;
  const int quad = lane >> 4, r = lane & 15;
  const int h = blockIdx.y, b = blockIdx.z;
  const int q0 = blockIdx.x * 128;
  const size_t hoff = (size_t)h * 64;
  const ushort_t* Qb = Q + ((size_t)b * 1024 + q0) * 512 + hoff;
  const ushort_t* Kb = Kmat + (size_t)b * Lk * 512 + hoff;
  const ushort_t* Vb = V + (size_t)b * Lk * 512 + hoff;

  short8 qb[2][2];
#pragma unroll
  for (int ct = 0; ct < 2; ++ct)
#pragma unroll
    for (int ki = 0; ki < 2; ++ki)
      qb[ct][ki] = *(const short8*)(Qb + (size_t)(w * 32 + ct * 16 + r) * 512 +
                                    ki * 32 + quad * 8);

  f32x4 oacc[4][2];
#pragma unroll
  for (int rt = 0; rt < 4; ++rt)
#pragma unroll
    for (int ct = 0; ct < 2; ++ct) oacc[rt][ct] = (f32x4){0.f, 0.f, 0.f, 0.f};
  float m_[2] = {-1e30f, -1e30f};
  float l_[2] = {0.f, 0.f};

  uint4 kr[2], vr[2], kn[2], vn[2];
  auto ldkv = [&](int k0, uint4* kp, uint4* vp) {
#pragma unroll
    for (int j = 0; j < 2; ++j) {
      const int dof = (w + 4 * j) * 8;
      kp[j] = *(const uint4*)(Kb + (size_t)(k0 + lane) * 512 + dof);
      vp[j] = *(const uint4*)(Vb + (size_t)(k0 + lane) * 512 + dof);
    }
  };
  auto stkv = [&](const uint4* kp, const uint4* vp) {
#pragma unroll
    for (int j = 0; j < 2; ++j) {
      const int dof = (w + 4 * j) * 8;
      *(uint4*)&Ks[lane][dof] = kp[j];
      const ushort_t* vv = (const ushort_t*)&vp[j];
#pragma unroll
      for (int i = 0; i < 8; ++i) Vt[dof + i][lane] = vv[i];  // transpose
    }
  };

  ldkv(0, kr, vr);
  const int nch = Lk >> 6;
  for (int c = 0; c < nch; ++c) {
    stkv(kr, vr);
    __syncthreads();
    if (c + 1 < nch) ldkv((c + 1) << 6, kn, vn);

    // ---- S^T = K · Q^T ----
    f32x4 sacc[4][2];
#pragma unroll
    for (int rt = 0; rt < 4; ++rt)
#pragma unroll
      for (int ct = 0; ct < 2; ++ct) sacc[rt][ct] = (f32x4){0.f, 0.f, 0.f, 0.f};
#pragma unroll
    for (int ki = 0; ki < 2; ++ki) {
      short8 kf[4];
#pragma unroll
      for (int rt = 0; rt < 4; ++rt)
        kf[rt] = *(const short8*)&Ks[rt * 16 + r][ki * 32 + quad * 8];
#pragma unroll
      for (int rt = 0; rt < 4; ++rt)
#pragma unroll
        for (int ct = 0; ct < 2; ++ct)
          sacc[rt][ct] = MFMA16(kf[rt], qb[ct][ki], sacc[rt][ct]);
    }

    // ---- online softmax ----
#pragma unroll
    for (int ct = 0; ct < 2; ++ct) {
      float vmax = sacc[0][ct][0];
#pragma unroll
      for (int rt = 0; rt < 4; ++rt)
#pragma unroll
        for (int reg = 0; reg < 4; ++reg) vmax = fmaxf(vmax, sacc[rt][ct][reg]);
      vmax = fmaxf(vmax, __shfl_xor(vmax, 16, 64));
      vmax = fmaxf(vmax, __shfl_xor(vmax, 32, 64));
      const float mnew = fmaxf(m_[ct], vmax * 0.125f);
      const float corr = __expf(m_[ct] - mnew);
      m_[ct] = mnew;
      float ps = 0.f;
#pragma unroll
      for (int rt = 0; rt < 4; ++rt) {
        float p0 = __expf(fmaf(sacc[rt][ct][0], 0.125f, -mnew));
        float p1 = __expf(fmaf(sacc[rt][ct][1], 0.125f, -mnew));
        float p2 = __expf(fmaf(sacc[rt][ct][2], 0.125f, -mnew));
        float p3 = __expf(fmaf(sacc[rt][ct][3], 0.125f, -mnew));
        ps += (p0 + p1) + (p2 + p3);
        uint2 pk;
        pk.x = (unsigned)f2bf(p0) | ((unsigned)f2bf(p1) << 16);
        pk.y = (unsigned)f2bf(p2) | ((unsigned)f2bf(p3) << 16);
        *(uint2*)&Pt[w][ct * 16 + r][rt * 16 + quad * 4] = pk;
      }
      ps += __shfl_xor(ps, 16, 64);
      ps += __shfl_xor(ps, 32, 64);
      l_[ct] = l_[ct] * corr + ps;
#pragma unroll
      for (int rt = 0; rt < 4; ++rt)
#pragma unroll
        for (int reg = 0; reg < 4; ++reg) oacc[rt][ct][reg] *= corr;
    }

    // ---- O^T += V^T · P^T ----
#pragma unroll
    for (int ki = 0; ki < 2; ++ki) {
      short8 vf[4], pf[2];
#pragma unroll
      for (int rt = 0; rt < 4; ++rt)
        vf[rt] = *(const short8*)&Vt[rt * 16 + r][ki * 32 + quad * 8];
#pragma unroll
      for (int ct = 0; ct < 2; ++ct)
        pf[ct] = *(const short8*)&Pt[w][ct * 16 + r][ki * 32 + quad * 8];
#pragma unroll
      for (int rt = 0; rt < 4; ++rt)
#pragma unroll
        for (int ct = 0; ct < 2; ++ct)
          oacc[rt][ct] = MFMA16(vf[rt], pf[ct], oacc[rt][ct]);
    }
    __syncthreads();
#pragma unroll
    for (int j = 0; j < 2; ++j) { kr[j] = kn[j]; vr[j] = vn[j]; }
  }

  // ---- epilogue ----
#pragma unroll
  for (int ct = 0; ct < 2; ++ct) {
    const float inv = 1.0f / l_[ct];
    const int qg = q0 + w * 32 + ct * 16 + r;
    ushort_t* op = O + ((size_t)b * 1024 + qg) * 512 + hoff;
#pragma unroll
    for (int rt = 0; rt < 4; ++rt) {
      uint2 pk;
      pk.x = (unsigned)f2bf(oacc[rt][ct][0] * inv) |
             ((unsigned)f2bf(oacc[rt][ct][1] * inv) << 16);
      pk.y = (unsigned)f2bf(oacc[rt][ct][2] * inv) |
             ((unsigned)f2bf(oacc[rt][ct][3] * inv) << 16);
      *(uint2*)(op + rt * 16 + quad * 4) = pk;
    }
  }
}

// ---------------------------------------------------------------------------
// Kernel 6: MoE fc_in for ONE expert slot ks.  grid (16, 8, B), 256 thr.
// ---------------------------------------------------------------------------
__global__ __launch_bounds__(256) void moe_fcin(
    const ushort_t* __restrict__ Xm, const ushort_t* __restrict__ WiT,
    const float* __restrict__ Bi, const float* __restrict__ tw,
    const int* __restrict__ ti, ushort_t* __restrict__ Hid, int ks)
{
  __shared__ ushort_t As[2][4096];
  __shared__ ushort_t Bv[2][4096];
  __shared__ ushort_t Bg[2][4096];
  const int t = threadIdx.x;
  const int w = t >> 6, lane = t & 63;
  const int quad = lane >> 4, r = lane & 15;
  const int wm = w >> 1, wn = w & 1;
  const int b = blockIdx.z;
  const int e = ti[b * 2 + ks];
  const float wq = tw[b * 2 + ks];
  const int r0 = blockIdx.y * 128, n0 = blockIdx.x * 128;
  const ushort_t* Ab = Xm + ((size_t)b * 1024 + r0) * 512;
  const ushort_t* Wv = WiT + (size_t)e * 4096 * 512 + (size_t)n0 * 512;
  const ushort_t* Wg = Wv + (size_t)2048 * 512;
  f32x4 av[4][4], ag[4][4];
#pragma unroll
  for (int i = 0; i < 4; ++i)
#pragma unroll
    for (int j = 0; j < 4; ++j) {
      av[i][j] = (f32x4){0.f, 0.f, 0.f, 0.f};
      ag[i][j] = (f32x4){0.f, 0.f, 0.f, 0.f};
    }
  stage_tile(Ab, 512, As[0]);
  stage_tile(Wv, 512, Bv[0]);
  stage_tile(Wg, 512, Bg[0]);
  __syncthreads();
  for (int it = 0; it < 16; ++it) {
    const int cur = it & 1;
    if (it + 1 < 16) {
      stage_tile(Ab + (it + 1) * 32, 512, As[cur ^ 1]);
      stage_tile(Wv + (it + 1) * 32, 512, Bv[cur ^ 1]);
      stage_tile(Wg + (it + 1) * 32, 512, Bg[cur ^ 1]);
    }
    short8 af[4], bv[4], bg[4];
#pragma unroll
    for (int i = 0; i < 4; ++i)
      af[i] = *(const short8*)&As[cur][(wm * 64 + i * 16 + r) * 32 + quad * 8];
#pragma unroll
    for (int j = 0; j < 4; ++j) {
      bv[j] = *(const short8*)&Bv[cur][(wn * 64 + j * 16 + r) * 32 + quad * 8];
      bg[j] = *(const short8*)&Bg[cur][(wn * 64 + j * 16 + r) * 32 + quad * 8];
    }
#pragma unroll
    for (int i = 0; i < 4; ++i)
#pragma unroll
      for (int j = 0; j < 4; ++j) {
        av[i][j] = MFMA16(af[i], bv[j], av[i][j]);
        ag[i][j] = MFMA16(af[i], bg[j], ag[i][j]);
      }
    __syncthreads();
  }
  ushort_t* Hb = Hid + (size_t)b * 1024 * 2048;
#pragma unroll
  for (int j = 0; j < 4; ++j) {
    const int col = n0 + wn * 64 + j * 16 + r;
    const float bval = Bi[(size_t)e * 4096 + col];
    const float bgat = Bi[(size_t)e * 4096 + 2048 + col];
#pragma unroll
    for (int i = 0; i < 4; ++i)
#pragma unroll
      for (int reg = 0; reg < 4; ++reg) {
        const int lrow = r0 + wm * 64 + i * 16 + quad * 4 + reg;
        float vv = av[i][j][reg] + bval;
        float gg = ag[i][j][reg] + bgat;
        float hv = vv * (gg / (1.0f + __expf(-gg))) * wq;
        Hb[(size_t)lrow * 2048 + col] = f2bf(hv);
      }
  }
}

// ---------------------------------------------------------------------------
// Kernel 7: MoE fc_out for ONE slot.  grid (4, 8, B), 256 thr.
// first=1: Out = X2 + acc + (tw0*bo_e0 + tw1*bo_e1);  first=0: Out += acc
// ---------------------------------------------------------------------------
__global__ __launch_bounds__(256) void moe_fcout(
    const ushort_t* __restrict__ Hid, const ushort_t* __restrict__ WoT,
    const float* __restrict__ Bo, const float* __restrict__ X2,
    const float* __restrict__ tw, const int* __restrict__ ti,
    float* __restrict__ Out, int ks, int first)
{
  __shared__ ushort_t As[2][4096];
  __shared__ ushort_t Bs[2][4096];
  const int t = threadIdx.x;
  const int w = t >> 6, lane = t & 63;
  const int quad = lane >> 4, r = lane & 15;
  const int wm = w >> 1, wn = w & 1;
  const int b = blockIdx.z;
  const int e = ti[b * 2 + ks];
  const int r0 = blockIdx.y * 128, n0 = blockIdx.x * 128;
  f32x4 acc[4][4];
#pragma unroll
  for (int i = 0; i < 4; ++i)
#pragma unroll
    for (int j = 0; j < 4; ++j) acc[i][j] = (f32x4){0.f, 0.f, 0.f, 0.f};
  const ushort_t* Ab = Hid + ((size_t)b * 1024 + r0) * 2048;
  const ushort_t* Bb = WoT + (size_t)e * 512 * 2048 + (size_t)n0 * 2048;
  stage_tile(Ab, 2048, As[0]);
  stage_tile(Bb, 2048, Bs[0]);
  __syncthreads();
  for (int it = 0; it < 64; ++it) {
    const int cur = it & 1;
    if (it + 1 < 64) {
      stage_tile(Ab + (it + 1) * 32, 2048, As[cur ^ 1]);
      stage_tile(Bb + (it + 1) * 32, 2048, Bs[cur ^ 1]);
    }
    short8 af[4], bfg[4];
#pragma unroll
    for (int i = 0; i < 4; ++i)
      af[i] = *(const short8*)&As[cur][(wm * 64 + i * 16 + r) * 32 + quad * 8];
#pragma unroll
    for (int j = 0; j < 4; ++j)
      bfg[j] = *(const short8*)&Bs[cur][(wn * 64 + j * 16 + r) * 32 + quad * 8];
#pragma unroll
    for (int i = 0; i < 4; ++i)
#pragma unroll
      for (int j = 0; j < 4; ++j)
        acc[i][j] = MFMA16(af[i], bfg[j], acc[i][j]);
    __syncthreads();
  }
  const int e0 = ti[b * 2], e1 = ti[b * 2 + 1];
  const float tw0 = tw[b * 2], tw1 = tw[b * 2 + 1];
#pragma unroll
  for (int j = 0; j < 4; ++j) {
    const int col = n0 + wn * 64 + j * 16 + r;
    const float badd = first ? (tw0 * Bo[(size_t)e0 * 512 + col] +
                                tw1 * Bo[(size_t)e1 * 512 + col]) : 0.f;
#pragma unroll
    for (int i = 0; i < 4; ++i)
#pragma unroll
      for (int reg = 0; reg < 4; ++reg) {
        const size_t row = (size_t)b * 1024 + r0 + wm * 64 + i * 16 + quad * 4 + reg;
        const size_t idx = row * 512 + col;
        const float base = first ? X2[idx] : Out[idx];
        Out[idx] = base + acc[i][j][reg] + badd;
      }
  }
}

// ---------------------------------------------------------------------------
// Launch.  Workspace: 93 MiB total.
// ---------------------------------------------------------------------------
extern "C" void kernel_launch(void* const* d_in, const int* in_sizes, int n_in,
                              void* d_out, int out_size, void* d_ws, size_t ws_size,
                              hipStream_t stream) {
  const float* x        = (const float*)d_in[0];
  const float* scene    = (const float*)d_in[1];
  const float* t_in     = (const float*)d_in[2];
  const float* sn_g     = (const float*)d_in[3];
  const float* sn_b     = (const float*)d_in[4];
  const float* ca_wq    = (const float*)d_in[5];
  const float* ca_bq    = (const float*)d_in[6];
  const float* ca_wk    = (const float*)d_in[7];
  const float* ca_bk    = (const float*)d_in[8];
  const float* ca_wv    = (const float*)d_in[9];
  const float* ca_bv    = (const float*)d_in[10];
  const float* ca_wo    = (const float*)d_in[11];
  const float* ca_bo    = (const float*)d_in[12];
  const float* sa_wq    = (const float*)d_in[13];
  const float* sa_bq    = (const float*)d_in[14];
  const float* sa_wk    = (const float*)d_in[15];
  const float* sa_bk    = (const float*)d_in[16];
  const float* sa_wv    = (const float*)d_in[17];
  const float* sa_bv    = (const float*)d_in[18];
  const float* sa_wo    = (const float*)d_in[19];
  const float* sa_bo    = (const float*)d_in[20];
  const float* ne_w1    = (const float*)d_in[21];
  const float* ne_b1    = (const float*)d_in[22];
  const float* ne_w2    = (const float*)d_in[23];
  const float* ne_b2    = (const float*)d_in[24];
  const float* ncsa_w   = (const float*)d_in[25];
  const float* ncsa_b   = (const float*)d_in[26];
  const float* moe_w    = (const float*)d_in[27];
  const float* moe_b    = (const float*)d_in[28];
  const float* router_w = (const float*)d_in[29];
  const float* fc_in_w  = (const float*)d_in[30];
  const float* fc_in_b  = (const float*)d_in[31];
  const float* fc_out_w = (const float*)d_in[32];
  const float* fc_out_b = (const float*)d_in[33];
  float* out = (float*)d_out;

  // ---- workspace layout (MiB offsets; 93 MiB total) ----
  char* W = (char*)d_ws;
  const size_t MB = 1u << 20;
  float* ncsa_mod = (float*)W;
  float* moe_mod  = ncsa_mod + 8192;
  float* tw       = moe_mod + 8192;
  int*   ti       = (int*)(tw + 16);
  float* nc_ws    = (float*)(ti + 16);            // [8][256]
  ushort_t* wT      = (ushort_t*)(W + 1 * MB);
  ushort_t* fciT    = (ushort_t*)(W + 5 * MB);
  ushort_t* fcoT    = (ushort_t*)(W + 37 * MB);
  ushort_t* xin_bf  = (ushort_t*)(W + 53 * MB);
  ushort_t* attn_bf = xin_bf;
  ushort_t* scene_bf= (ushort_t*)(W + 61 * MB);
  ushort_t* qf = (ushort_t*)(W + 65 * MB);
  ushort_t* kf = (ushort_t*)(W + 73 * MB);
  ushort_t* vf = (ushort_t*)(W + 81 * MB);
  ushort_t* hid = (ushort_t*)(W + 61 * MB);
  float* x1 = out;

  const int WSZ = 512 * 512;

  // noise path: embed+router (8 blocks), then mods (64 blocks)
  noise_embed<<<dim3(B_), dim3(256), 0, stream>>>(
      t_in, ne_w1, ne_b1, ne_w2, ne_b2, router_w, nc_ws, tw, ti);
  mod_proj<<<dim3(B_, 8), dim3(256), 0, stream>>>(
      nc_ws, ncsa_w, ncsa_b, moe_w, moe_b, ncsa_mod, moe_mod);

  // weight prep: 8 dense transposes in one dispatch + expert transposes
  P8 dsrc;
  dsrc.p[0] = ca_wq; dsrc.p[1] = ca_wk; dsrc.p[2] = ca_wv; dsrc.p[3] = ca_wo;
  dsrc.p[4] = sa_wq; dsrc.p[5] = sa_wk; dsrc.p[6] = sa_wv; dsrc.p[7] = sa_wo;
  transpose_cvt8<<<dim3(16, 16, 8), 256, 0, stream>>>(dsrc, wT);
  transpose_cvt<<<dim3(128, 16, 8), 256, 0, stream>>>(fc_in_w, fciT, 512, 4096,
                                                      (long)512 * 4096, (long)512 * 4096);
  transpose_cvt<<<dim3(16, 64, 8), 256, 0, stream>>>(fc_out_w, fcoT, 2048, 512,
                                                     (long)2048 * 512, (long)2048 * 512);
  cvt_bf16<<<dim3(2048), 256, 0, stream>>>(scene, scene_bf);

  // scene cross-attention
  ln_mod_kernel<<<dim3(8192), 256, 0, stream>>>(x, sn_g, sn_b, nullptr, xin_bf);
  gemm_bf16<<<dim3(4, 64), 256, 0, stream>>>(xin_bf, wT + 0 * WSZ, ca_bq, nullptr, qf, 8192, 512, 512, 1);
  gemm_bf16<<<dim3(4, 32), 256, 0, stream>>>(scene_bf, wT + 1 * WSZ, ca_bk, nullptr, kf, 4096, 512, 512, 1);
  gemm_bf16<<<dim3(4, 32), 256, 0, stream>>>(scene_bf, wT + 2 * WSZ, ca_bv, nullptr, vf, 4096, 512, 512, 1);
  fattn_mfma<<<dim3(8, NH_, B_), 256, 0, stream>>>(qf, kf, vf, attn_bf, NS_);
  gemm_bf16<<<dim3(4, 64), 256, 0, stream>>>(attn_bf, wT + 3 * WSZ, ca_bo, x, x1, 8192, 512, 512, 0);

  // noise-conditioned self-attention (AdaLN)
  ln_mod_kernel<<<dim3(8192), 256, 0, stream>>>(x1, nullptr, nullptr, ncsa_mod, xin_bf);
  gemm_bf16<<<dim3(4, 64), 256, 0, stream>>>(xin_bf, wT + 4 * WSZ, sa_bq, nullptr, qf, 8192, 512, 512, 1);
  gemm_bf16<<<dim3(4, 64), 256, 0, stream>>>(xin_bf, wT + 5 * WSZ, sa_bk, nullptr, kf, 8192, 512, 512, 1);
  gemm_bf16<<<dim3(4, 64), 256, 0, stream>>>(xin_bf, wT + 6 * WSZ, sa_bv, nullptr, vf, 8192, 512, 512, 1);
  fattn_mfma<<<dim3(8, NH_, B_), 256, 0, stream>>>(qf, kf, vf, attn_bf, L_);
  gemm_bf16<<<dim3(4, 64), 256, 0, stream>>>(attn_bf, wT + 7 * WSZ, sa_bo, out, out, 8192, 512, 512, 0);

  // MoE
  ln_mod_kernel<<<dim3(8192), 256, 0, stream>>>(out, nullptr, nullptr, moe_mod, xin_bf);
  moe_fcin<<<dim3(16, 8, B_), 256, 0, stream>>>(xin_bf, fciT, fc_in_b, tw, ti, hid, 0);
  moe_fcout<<<dim3(4, 8, B_), 256, 0, stream>>>(hid, fcoT, fc_out_b, out, tw, ti, out, 0, 1);
  moe_fcin<<<dim3(16, 8, B_), 256, 0, stream>>>(xin_bf, fciT, fc_in_b, tw, ti, hid, 1);
  moe_fcout<<<dim3(4, 8, B_), 256, 0, stream>>>(hid, fcoT, fc_out_b, out, tw, ti, out, 1, 0);
}